// Round 2
// baseline (239.988 us; speedup 1.0000x reference)
//
#include <hip/hip_runtime.h>

#define NPTS 8192
#define NB 4
#define NCH 128
#define DQK 48
#define TK 64
#define SPLIT 4
#define KEYS_PER (NPTS / SPLIT)   // 2048
#define ROUNDS (KEYS_PER / TK)    // 32
#define SH2 28.853901f            // 20 * log2(e)
#define LOG2E 1.4426950408889634f

typedef unsigned short ushort_t;
typedef unsigned int uint_t;
typedef __attribute__((ext_vector_type(8))) short bf16x8;
typedef __attribute__((ext_vector_type(4))) float f32x4;
typedef __attribute__((ext_vector_type(16))) float f32x16;

static __device__ __forceinline__ ushort_t f2bf(float x) {
  union { float f; uint_t u; } v; v.f = x;
  uint_t r = v.u + 0x7fffu + ((v.u >> 16) & 1u);
  return (ushort_t)(r >> 16);
}
static __device__ __forceinline__ float bf2f(ushort_t u) {
  union { uint_t i; float f; } v; v.i = ((uint_t)u) << 16; return v.f;
}
// sigma16: swap middle two 4-blocks of each 16-group (involution).
// Makes S^T C-layout regs directly usable as the PV A-fragment.
static __device__ __forceinline__ int sig16(int n) {
  int g2 = (n >> 2) & 3;
  return (g2 == 1 || g2 == 2) ? (n ^ 0xC) : n;
}

typedef __attribute__((address_space(1))) void void_g;
typedef __attribute__((address_space(3))) void void_l;
static __device__ __forceinline__ void gload_lds16(const ushort_t* g, ushort_t* l) {
  __builtin_amdgcn_global_load_lds((void_g*)(ushort_t*)g, (void_l*)l, 16, 0, 0);
}

// ---------------------------------------------------------------------------
// Weight prep: W -> A-fragment-ordered bf16 Wb[z][ks][lane][8] (log2e folded
// into z=0), plus fused scaled bias bias_pre[192]. 6 blocks, one z each.
// ---------------------------------------------------------------------------
__global__ __launch_bounds__(512, 1)
void wprep_kernel(const float* __restrict__ Wq, const float* __restrict__ bq,
                  const float* __restrict__ Wk, const float* __restrict__ bk,
                  const float* __restrict__ Wv, const float* __restrict__ bv,
                  ushort_t* __restrict__ Wb, float* __restrict__ bias_pre) {
  const int z = blockIdx.x;
  const int ks = threadIdx.x >> 6;
  const int lane = threadIdx.x & 63;
  const int l31 = lane & 31, h = lane >> 5;
  const float* W = (z == 0) ? Wq : (z == 1) ? Wk : (Wv + (size_t)(z - 2) * 32 * 128);
  const float sc = (z == 0) ? LOG2E : 1.0f;
  const float* wr = W + l31 * 128 + ks * 16 + h * 8;
  union { ushort_t u[8]; bf16x8 v; } p;
#pragma unroll
  for (int j = 0; j < 8; ++j) p.u[j] = f2bf(wr[j] * sc);
  *(bf16x8*)(Wb + ((size_t)(z * 8 + ks) * 64 + lane) * 8) = p.v;
  if (z == 0 && threadIdx.x < 192) {
    int i = threadIdx.x;
    bias_pre[i] = (i < 32) ? bq[i] * LOG2E : (i < 64) ? bk[i - 32] : bv[i - 64];
  }
}

// ---------------------------------------------------------------------------
// MFMA projections, fused over all 6 bands: x B-frags loaded+converted ONCE
// per wave (32 n-cols), reused for 48 MFMAs. A-frags from pre-packed Wb
// (coalesced 16B loads). C layout: col = lane&31, row = (r&3)+8*(r>>2)+4h.
// z=0: Qb rows (+xhat, log2e-scaled), z=1: Kb rows (+xhat), z=2..5: Vt with
// sigma16-permuted key index. Softmax shift folded into slot 35:
// Q[35] = -SH2, K[35] = 1.0 (uniform per-row additive constant -> cancels
// exactly in O/L normalization) => attn does exp2(S) with no subtract.
// ---------------------------------------------------------------------------
__global__ __launch_bounds__(256, 4)
void projm2_kernel(const float* __restrict__ x, const float* __restrict__ xyz,
                   const ushort_t* __restrict__ Wb,
                   const float* __restrict__ bias_pre,
                   ushort_t* __restrict__ Qb, ushort_t* __restrict__ Kb,
                   ushort_t* __restrict__ Vt) {
  const int tid = threadIdx.x;
  const int lane = tid & 63, wv = tid >> 6;
  const int l31 = lane & 31, h = lane >> 5;
  const int b = blockIdx.y;
  const int n = blockIdx.x * 128 + wv * 32 + l31;

  // B-frags from x (coalesced per c-row), converted once, reused 6x
  bf16x8 bfr[8];
  const float* xb = x + (size_t)b * NCH * NPTS + n;
#pragma unroll
  for (int ks = 0; ks < 8; ++ks) {
    const float* xc = xb + (size_t)(ks * 16 + h * 8) * NPTS;
    union { ushort_t u[8]; bf16x8 v; } p;
#pragma unroll
    for (int j = 0; j < 8; ++j) p.u[j] = f2bf(xc[(size_t)j * NPTS]);
    bfr[ks] = p.v;
  }

  // xhat (bands 0,1)
  float xa = xyz[((size_t)b * NPTS + n) * 3 + 0];
  float xc2 = xyz[((size_t)b * NPTS + n) * 3 + 1];
  float xd = xyz[((size_t)b * NPTS + n) * 3 + 2];
  float rinv = 1.0f / (sqrtf(xa * xa + xc2 * xc2 + xd * xd) + 1e-8f);

#pragma unroll 1
  for (int z = 0; z < 6; ++z) {
    f32x16 S;
#pragma unroll
    for (int r = 0; r < 16; ++r)
      S[r] = bias_pre[z * 32 + (r & 3) + 8 * (r >> 2) + 4 * h];
#pragma unroll
    for (int ks = 0; ks < 8; ++ks) {
      bf16x8 af = *(const bf16x8*)(Wb + ((size_t)(z * 8 + ks) * 64 + lane) * 8);
      S = __builtin_amdgcn_mfma_f32_32x32x16_bf16(af, bfr[ks], S, 0, 0, 0);
    }
    if (z <= 1) {
      float sc = (z == 0) ? LOG2E : 1.0f;
      ushort_t* dst = (z == 0 ? Qb : Kb) + ((size_t)b * NPTS + n) * DQK;
#pragma unroll
      for (int r = 0; r < 16; ++r)
        dst[(r & 3) + 8 * (r >> 2) + 4 * h] = f2bf(S[r]);
      float rn = 0.31622776601683794f * sc * rinv;
      union { ushort_t u[16]; bf16x8 v[2]; } t;
#pragma unroll
      for (int j = 0; j < 16; ++j) t.u[j] = 0;
      t.u[0] = f2bf(xa * rn); t.u[1] = f2bf(xc2 * rn); t.u[2] = f2bf(xd * rn);
      t.u[3] = (z == 0) ? f2bf(-SH2) : f2bf(1.0f);  // folded softmax shift
      *(bf16x8*)(dst + 32) = t.v[0];
      *(bf16x8*)(dst + 40) = t.v[1];
    } else {
      const int np = (n & ~15) | sig16(n & 15);  // key-permuted V storage
      const int c0 = (z - 2) * 32;
#pragma unroll
      for (int r = 0; r < 16; ++r)
        Vt[((size_t)b * NCH + c0 + (r & 3) + 8 * (r >> 2) + 4 * h) * NPTS + np] =
            f2bf(S[r]);
    }
  }
}

// ---------------------------------------------------------------------------
// MFMA flash attention, 32x32x16, 64 q/wave, 4 waves = 256 q/block.
// R9 RESTRUCTURE (post-mortem of R8): 32q/wave fixed occupancy (35%) and
// proved cross-pipe overlap exists, but DOUBLED LDS->reg traffic: per CU per
// round LDS = 16 waves x 22KB / 85 B/cyc = 4140 cyc = 60% (tallest pipe).
// Going back to 64 q/wave halves LDS bytes (each V frag feeds 2 PV MFMAs)
// -> LDS pipe 2070 cyc < MFMA 2841 cyc. Crucial difference vs the old
// serialized 64q version (R7, 108us): 4-wave blocks, grid 512 -> TWO
// independent barrier groups per CU; each SIMD = 1 wave of block A + 1 of
// block B -> phase drift -> A's exp overlaps B's MFMA. 128 acc + 128 arch
// = 256 regs -> 2 waves/SIMD exactly (launch_bounds (256,2)).
// Softmax shift pre-folded into slot 35 (no per-element subtract).
// V is sigma16-permuted so S^T C-regs pack directly into the PV A-frag.
// ---------------------------------------------------------------------------
__global__ __launch_bounds__(256, 2)
void attn32_kernel(const ushort_t* __restrict__ Qb, const ushort_t* __restrict__ Kb,
                   const ushort_t* __restrict__ Vt,
                   ushort_t* __restrict__ PACC, float* __restrict__ PL) {
  // frag f: K = kb*3+c (6), V = 6 + fch*4 + kk (16); each 64 lanes x 16B
  __shared__ __align__(16) ushort_t L[2][22][512];
  const int tid = threadIdx.x;
  const int lane = tid & 63, w = tid >> 6;   // w = 0..3
  const int l31 = lane & 31, h = lane >> 5;

  const int lin = blockIdx.x;
  const int bs = lin & 15;          // XCD x sees bs in {x, x+8}: 2 (b,seg) combos
  const int b = bs & 3, sseg = bs >> 2;
  const int qblk = lin >> 4;        // 0..31 (256-q blocks)
  const int q0w = qblk * 256 + w * 64;
  const int m00 = sseg * KEYS_PER;

  // persistent Q^T B-frags: q = q0w + g*32 + l31, d = c*16 + h*8 + j
  bf16x8 qf[2][3];
#pragma unroll
  for (int g = 0; g < 2; ++g)
#pragma unroll
    for (int c = 0; c < 3; ++c)
      qf[g][c] = *(const bf16x8*)(Qb + ((size_t)b * NPTS + q0w + g * 32 + l31) * DQK +
                                  c * 16 + h * 8);

  // staging: wave w handles frags {w, w+4, w+8, w+12, w+16, w+20(<22)}
  const ushort_t* gp[6];
  int fid[6], adv[6];
  const int nf = (w < 2) ? 6 : 5;
#pragma unroll
  for (int i = 0; i < 6; ++i) {
    int fi = w + 4 * i;
    fid[i] = fi;
    if (fi < 6) {
      int kb = fi / 3, c = fi - kb * 3;
      gp[i] = Kb + ((size_t)b * NPTS + m00 + kb * 32 + l31) * DQK + c * 16 + h * 8;
      adv[i] = TK * DQK;
    } else if (fi < 22) {
      int vi = fi - 6, fch = vi >> 2, kk = vi & 3;
      gp[i] = Vt + ((size_t)b * NCH + fch * 32 + l31) * NPTS + m00 + kk * 16 + h * 8;
      adv[i] = TK;
    }
  }

  f32x16 O[2][4];
#pragma unroll
  for (int g = 0; g < 2; ++g)
#pragma unroll
    for (int f = 0; f < 4; ++f) O[g][f] = (f32x16)(0.f);
  float ls0 = 0.f, ls1 = 0.f;

  // prologue: stage round 0 into buffer 0
#pragma unroll
  for (int i = 0; i < 6; ++i)
    if (i < nf) gload_lds16(gp[i], &L[0][fid[i]][0]);

#pragma unroll 1
  for (int t = 0; t < ROUNDS; ++t) {
    __syncthreads();  // auto vmcnt(0): buf[t&1] DMA (issued a full round ago) drained
    const int cur = t & 1;
    if (t + 1 < ROUNDS) {
#pragma unroll
      for (int i = 0; i < 6; ++i)
        if (i < nf) {
          gp[i] += adv[i];
          gload_lds16(gp[i], &L[cur ^ 1][fid[i]][0]);  // overlaps compute below
        }
    }

#pragma unroll
    for (int kb = 0; kb < 2; ++kb) {
      bf16x8 kf0 = *(const bf16x8*)(&L[cur][kb * 3 + 0][0] + lane * 8);
      bf16x8 kf1 = *(const bf16x8*)(&L[cur][kb * 3 + 1][0] + lane * 8);
      bf16x8 kf2 = *(const bf16x8*)(&L[cur][kb * 3 + 2][0] + lane * 8);

      uint_t pk[2][8];
#pragma unroll
      for (int g = 0; g < 2; ++g) {
        __builtin_amdgcn_s_setprio(1);
        f32x16 S = __builtin_amdgcn_mfma_f32_32x32x16_bf16(kf0, qf[g][0],
                                                           (f32x16)(0.f), 0, 0, 0);
        S = __builtin_amdgcn_mfma_f32_32x32x16_bf16(kf1, qf[g][1], S, 0, 0, 0);
        S = __builtin_amdgcn_mfma_f32_32x32x16_bf16(kf2, qf[g][2], S, 0, 0, 0);
        __builtin_amdgcn_s_setprio(0);
        // shift pre-folded via slot 35: p = exp2(S) directly
        float ts = 0.f;
#pragma unroll
        for (int i = 0; i < 8; ++i) {
          float p0 = __builtin_amdgcn_exp2f(S[2 * i]);
          float p1 = __builtin_amdgcn_exp2f(S[2 * i + 1]);
          ts += p0;
          ts += p1;
          pk[g][i] = __builtin_amdgcn_perm(__float_as_uint(p1), __float_as_uint(p0),
                                           0x07060302u);
        }
        if (g == 0) ls0 += ts; else ls1 += ts;
      }

      // sigma16-permuted V => C-regs pack directly into PV A-frags
#pragma unroll
      for (int kkl = 0; kkl < 2; ++kkl) {
        bf16x8 A[2];
#pragma unroll
        for (int g = 0; g < 2; ++g) {
          union { uint_t u[4]; bf16x8 v; } au;
          au.u[0] = pk[g][4 * kkl + 0];
          au.u[1] = pk[g][4 * kkl + 1];
          au.u[2] = pk[g][4 * kkl + 2];
          au.u[3] = pk[g][4 * kkl + 3];
          A[g] = au.v;
        }
        __builtin_amdgcn_s_setprio(1);
#pragma unroll
        for (int f = 0; f < 4; ++f) {
          bf16x8 vf = *(const bf16x8*)(&L[cur][6 + f * 4 + kb * 2 + kkl][0] + lane * 8);
          O[0][f] = __builtin_amdgcn_mfma_f32_32x32x16_bf16(A[0], vf, O[0][f], 0, 0, 0);
          O[1][f] = __builtin_amdgcn_mfma_f32_32x32x16_bf16(A[1], vf, O[1][f], 0, 0, 0);
        }
        __builtin_amdgcn_s_setprio(0);
      }
    }
  }

  // epilogue: PACC chunk index within 512-q block = (qblk&1)*8 + w*2 + g
  ls0 += __shfl_xor(ls0, 32);
  ls1 += __shfl_xor(ls1, 32);
  const size_t pb0 = (size_t)(bs * 16 + (qblk >> 1)) * 16 + (qblk & 1) * 8 + w * 2;
#pragma unroll
  for (int g = 0; g < 2; ++g) {
#pragma unroll
    for (int f = 0; f < 4; ++f) {
      union { ushort_t u[16]; bf16x8 v[2]; } pu;
#pragma unroll
      for (int r = 0; r < 16; ++r) pu.u[r] = f2bf(O[g][f][r]);
      size_t idx = ((pb0 + g) * 4 + f) * 1024 + (size_t)lane * 16;
      *(bf16x8*)(PACC + idx) = pu.v[0];
      *(bf16x8*)(PACC + idx + 8) = pu.v[1];
    }
    if (lane < 32)
      PL[(size_t)bs * NPTS + q0w + g * 32 + lane] = (g == 0) ? ls0 : ls1;
  }
}

// ---------------------------------------------------------------------------
// Merge 4 key-split partials + gamma + x, COALESCED output via LDS bounce.
// grid (qblk2 32, b 4, f 4); each block: 256 q x 32 ch.
// Phase 1: coalesced PACC reads, sum over s, x Linv, stage fp32 in LDS.
// Phase 2: wave w -> 8 ch rows; lane -> q=lane*4: contiguous 1KB load/stores.
// ---------------------------------------------------------------------------
#define MPITCH 268
__global__ __launch_bounds__(256, 4)
void merge4c_kernel(const ushort_t* __restrict__ PACC, const float* __restrict__ PL,
                    const float* __restrict__ x, const float* __restrict__ gamma,
                    float* __restrict__ out) {
  __shared__ float Linv[256];
  __shared__ float ldso[32 * MPITCH];
  const int tid = threadIdx.x;
  const int qblk2 = blockIdx.x, b = blockIdx.y, f = blockIdx.z;
  const int q0 = qblk2 * 256;

  float Ls = 0.f;
#pragma unroll
  for (int s = 0; s < 4; ++s)
    Ls += PL[(size_t)(s * 4 + b) * NPTS + q0 + tid];
  Linv[tid] = gamma[0] / Ls;
  __syncthreads();

  const int ww = tid >> 6, lane = tid & 63, l31 = lane & 31, h = lane >> 5;

#pragma unroll
  for (int g = 0; g < 2; ++g) {
    float acc[16];
#pragma unroll
    for (int r = 0; r < 16; ++r) acc[r] = 0.f;
#pragma unroll
    for (int s = 0; s < 4; ++s) {
      size_t idx = (((((size_t)(s * 4 + b) * 16 + (qblk2 >> 1)) * 8 +
                      (qblk2 & 1) * 4 + ww) * 2 + g) * 4 + f) * 1024 +
                   (size_t)lane * 16;
      bf16x8 a0 = *(const bf16x8*)(PACC + idx);
      bf16x8 a1 = *(const bf16x8*)(PACC + idx + 8);
#pragma unroll
      for (int r = 0; r < 8; ++r) {
        acc[r] += bf2f((ushort_t)a0[r]);
        acc[8 + r] += bf2f((ushort_t)a1[r]);
      }
    }
    const int qb = ww * 64 + g * 32 + 4 * h;
#pragma unroll
    for (int rr = 0; rr < 4; ++rr) {
      int q = qb + 8 * rr;
      f32x4 v;
#pragma unroll
      for (int i = 0; i < 4; ++i) v[i] = acc[rr * 4 + i] * Linv[q + i];
      *(f32x4*)&ldso[l31 * MPITCH + q] = v;  // ch_local = l31
    }
  }
  __syncthreads();

  // phase 2: coalesced: wave ww -> ch rows ww*8..+7, lane -> q = lane*4
  const float* xb = x + ((size_t)b * NCH + f * 32) * NPTS + q0;
  float* ob = out + ((size_t)b * NCH + f * 32) * NPTS + q0;
#pragma unroll
  for (int rr = 0; rr < 8; ++rr) {
    int ch = ww * 8 + rr;
    f32x4 v = *(const f32x4*)&ldso[ch * MPITCH + lane * 4];
    f32x4 xv = *(const f32x4*)(xb + (size_t)ch * NPTS + lane * 4);
    v += xv;
    *(f32x4*)(ob + (size_t)ch * NPTS + lane * 4) = v;
  }
}

// ---------------------------------------------------------------------------
extern "C" void kernel_launch(void* const* d_in, const int* in_sizes, int n_in,
                              void* d_out, int out_size, void* d_ws,
                              size_t ws_size, hipStream_t stream) {
  const float* x     = (const float*)d_in[0];
  const float* xyz   = (const float*)d_in[1];
  const float* Wq    = (const float*)d_in[2];
  const float* bq    = (const float*)d_in[3];
  const float* Wk    = (const float*)d_in[4];
  const float* bk    = (const float*)d_in[5];
  const float* Wv    = (const float*)d_in[6];
  const float* bv    = (const float*)d_in[7];
  const float* gamma = (const float*)d_in[8];
  float* out = (float*)d_out;

  const size_t BN = (size_t)NB * NPTS;
  ushort_t* Qb = (ushort_t*)d_ws;
  ushort_t* Kb = Qb + BN * DQK;
  ushort_t* Vt = Kb + BN * DQK;
  ushort_t* PACC = Vt + BN * NCH;   // 16 bs * 16 qblk * 16 chunk * 4 f * 1024
  float* PL = (float*)(PACC + (size_t)16 * 16 * 8 * 2 * 4 * 1024);
  ushort_t* Wb = (ushort_t*)(PL + 16 * BN / 2);  // 6*8*64*8 = 24576 ushort
  float* bias_pre = (float*)(Wb + 6 * 8 * 64 * 8);

  wprep_kernel<<<6, 512, 0, stream>>>(Wq, bq, Wk, bk, Wv, bv, Wb, bias_pre);
  projm2_kernel<<<dim3(NPTS / 128, NB), 256, 0, stream>>>(
      x, xyz, Wb, bias_pre, Qb, Kb, Vt);
  attn32_kernel<<<512, 256, 0, stream>>>(Qb, Kb, Vt, PACC, PL);
  merge4c_kernel<<<dim3(32, NB, 4), 256, 0, stream>>>(PACC, PL, x, gamma, out);
  (void)in_sizes; (void)n_in; (void)out_size; (void)ws_size;
}

// Round 3
// 197.563 us; speedup vs baseline: 1.2147x; 1.2147x over previous
//
#include <hip/hip_runtime.h>

#define NPTS 8192
#define NB 4
#define NCH 128
#define DQK 48
#define TK 64
#define SPLIT 4
#define KEYS_PER (NPTS / SPLIT)   // 2048
#define ROUNDS (KEYS_PER / TK)    // 32
#define SH2 28.853901f            // 20 * log2(e)
#define LOG2E 1.4426950408889634f

typedef unsigned short ushort_t;
typedef unsigned int uint_t;
typedef __attribute__((ext_vector_type(8))) short bf16x8;
typedef __attribute__((ext_vector_type(4))) float f32x4;
typedef __attribute__((ext_vector_type(16))) float f32x16;

static __device__ __forceinline__ ushort_t f2bf(float x) {
  union { float f; uint_t u; } v; v.f = x;
  uint_t r = v.u + 0x7fffu + ((v.u >> 16) & 1u);
  return (ushort_t)(r >> 16);
}
static __device__ __forceinline__ float bf2f(ushort_t u) {
  union { uint_t i; float f; } v; v.i = ((uint_t)u) << 16; return v.f;
}
// sigma16: swap middle two 4-blocks of each 16-group (involution).
// Makes S^T C-layout regs directly usable as the PV A-fragment.
static __device__ __forceinline__ int sig16(int n) {
  int g2 = (n >> 2) & 3;
  return (g2 == 1 || g2 == 2) ? (n ^ 0xC) : n;
}

typedef __attribute__((address_space(1))) void void_g;
typedef __attribute__((address_space(3))) void void_l;
static __device__ __forceinline__ void gload_lds16(const ushort_t* g, ushort_t* l) {
  __builtin_amdgcn_global_load_lds((void_g*)(ushort_t*)g, (void_l*)l, 16, 0, 0);
}

// ---------------------------------------------------------------------------
// Weight prep: W -> A-fragment-ordered bf16 Wb[z][ks][lane][8] (log2e folded
// into z=0), plus fused scaled bias bias_pre[192]. 6 blocks, one z each.
// ---------------------------------------------------------------------------
__global__ __launch_bounds__(512, 1)
void wprep_kernel(const float* __restrict__ Wq, const float* __restrict__ bq,
                  const float* __restrict__ Wk, const float* __restrict__ bk,
                  const float* __restrict__ Wv, const float* __restrict__ bv,
                  ushort_t* __restrict__ Wb, float* __restrict__ bias_pre) {
  const int z = blockIdx.x;
  const int ks = threadIdx.x >> 6;
  const int lane = threadIdx.x & 63;
  const int l31 = lane & 31, h = lane >> 5;
  const float* W = (z == 0) ? Wq : (z == 1) ? Wk : (Wv + (size_t)(z - 2) * 32 * 128);
  const float sc = (z == 0) ? LOG2E : 1.0f;
  const float* wr = W + l31 * 128 + ks * 16 + h * 8;
  union { ushort_t u[8]; bf16x8 v; } p;
#pragma unroll
  for (int j = 0; j < 8; ++j) p.u[j] = f2bf(wr[j] * sc);
  *(bf16x8*)(Wb + ((size_t)(z * 8 + ks) * 64 + lane) * 8) = p.v;
  if (z == 0 && threadIdx.x < 192) {
    int i = threadIdx.x;
    bias_pre[i] = (i < 32) ? bq[i] * LOG2E : (i < 64) ? bk[i - 32] : bv[i - 64];
  }
}

// ---------------------------------------------------------------------------
// MFMA projections, fused over all 6 bands: x B-frags loaded+converted ONCE
// per wave (32 n-cols), reused for 48 MFMAs. A-frags from pre-packed Wb
// (coalesced 16B loads). C layout: col = lane&31, row = (r&3)+8*(r>>2)+4h.
// z=0: Qb rows (+xhat, log2e-scaled), z=1: Kb rows (+xhat), z=2..5: Vt with
// sigma16-permuted key index. Softmax shift folded into slot 35:
// Q[35] = -SH2, K[35] = 1.0 (uniform per-row additive constant -> cancels
// exactly in O/L normalization) => attn does exp2(S) with no subtract.
// ---------------------------------------------------------------------------
__global__ __launch_bounds__(256, 4)
void projm2_kernel(const float* __restrict__ x, const float* __restrict__ xyz,
                   const ushort_t* __restrict__ Wb,
                   const float* __restrict__ bias_pre,
                   ushort_t* __restrict__ Qb, ushort_t* __restrict__ Kb,
                   ushort_t* __restrict__ Vt) {
  const int tid = threadIdx.x;
  const int lane = tid & 63, wv = tid >> 6;
  const int l31 = lane & 31, h = lane >> 5;
  const int b = blockIdx.y;
  const int n = blockIdx.x * 128 + wv * 32 + l31;

  // B-frags from x (coalesced per c-row), converted once, reused 6x
  bf16x8 bfr[8];
  const float* xb = x + (size_t)b * NCH * NPTS + n;
#pragma unroll
  for (int ks = 0; ks < 8; ++ks) {
    const float* xc = xb + (size_t)(ks * 16 + h * 8) * NPTS;
    union { ushort_t u[8]; bf16x8 v; } p;
#pragma unroll
    for (int j = 0; j < 8; ++j) p.u[j] = f2bf(xc[(size_t)j * NPTS]);
    bfr[ks] = p.v;
  }

  // xhat (bands 0,1)
  float xa = xyz[((size_t)b * NPTS + n) * 3 + 0];
  float xc2 = xyz[((size_t)b * NPTS + n) * 3 + 1];
  float xd = xyz[((size_t)b * NPTS + n) * 3 + 2];
  float rinv = 1.0f / (sqrtf(xa * xa + xc2 * xc2 + xd * xd) + 1e-8f);

#pragma unroll 1
  for (int z = 0; z < 6; ++z) {
    f32x16 S;
#pragma unroll
    for (int r = 0; r < 16; ++r)
      S[r] = bias_pre[z * 32 + (r & 3) + 8 * (r >> 2) + 4 * h];
#pragma unroll
    for (int ks = 0; ks < 8; ++ks) {
      bf16x8 af = *(const bf16x8*)(Wb + ((size_t)(z * 8 + ks) * 64 + lane) * 8);
      S = __builtin_amdgcn_mfma_f32_32x32x16_bf16(af, bfr[ks], S, 0, 0, 0);
    }
    if (z <= 1) {
      float sc = (z == 0) ? LOG2E : 1.0f;
      ushort_t* dst = (z == 0 ? Qb : Kb) + ((size_t)b * NPTS + n) * DQK;
#pragma unroll
      for (int r = 0; r < 16; ++r)
        dst[(r & 3) + 8 * (r >> 2) + 4 * h] = f2bf(S[r]);
      float rn = 0.31622776601683794f * sc * rinv;
      union { ushort_t u[16]; bf16x8 v[2]; } t;
#pragma unroll
      for (int j = 0; j < 16; ++j) t.u[j] = 0;
      t.u[0] = f2bf(xa * rn); t.u[1] = f2bf(xc2 * rn); t.u[2] = f2bf(xd * rn);
      t.u[3] = (z == 0) ? f2bf(-SH2) : f2bf(1.0f);  // folded softmax shift
      *(bf16x8*)(dst + 32) = t.v[0];
      *(bf16x8*)(dst + 40) = t.v[1];
    } else {
      const int np = (n & ~15) | sig16(n & 15);  // key-permuted V storage
      const int c0 = (z - 2) * 32;
#pragma unroll
      for (int r = 0; r < 16; ++r)
        Vt[((size_t)b * NCH + c0 + (r & 3) + 8 * (r >> 2) + 4 * h) * NPTS + np] =
            f2bf(S[r]);
    }
  }
}

// ---------------------------------------------------------------------------
// MFMA flash attention, 32x32x16, 32 q/wave, 8 waves = 256 q/block.
// R10 (post-mortem R8/R9): R8 (32q, 4 waves/SIMD) = 91us, LDS-read pipe
// tallest (16 waves x 22KB / 85 B/cyc = 4140 cyc/round = 60%). R9 (64q,
// 2 waves/SIMD) spilled (+19MB scratch traffic) and serialized: 151us.
// KEEP R8's occupancy-friendly 32q shape; cut LDS by reading K fragments
// DIRECTLY from global: K staging was a pure per-lane pass-through (DMA
// wrote lane*16B, read was lane*16B) and K per (b,seg) is 196KB -> L2-hit.
// LDS keeps only V (8-way shared across waves). Pipes per CU-round:
// LDS 3010, MFMA 2841, VALU 2670, L2 1714 cyc -> balanced.
// Softmax shift pre-folded into slot 35 (no per-element subtract).
// V is sigma16-permuted so S^T C-regs pack directly into the PV A-frag.
// ---------------------------------------------------------------------------
__global__ __launch_bounds__(512, 4)
void attn32_kernel(const ushort_t* __restrict__ Qb, const ushort_t* __restrict__ Kb,
                   const ushort_t* __restrict__ Vt,
                   ushort_t* __restrict__ PACC, float* __restrict__ PL) {
  // V frags only: frag v = fch*4 + kk (16 total); each 64 lanes x 16B
  __shared__ __align__(16) ushort_t L[2][16][512];
  const int tid = threadIdx.x;
  const int lane = tid & 63, w = tid >> 6;
  const int l31 = lane & 31, h = lane >> 5;

  const int lin = blockIdx.x;
  const int bs = lin & 15;          // XCD x sees bs in {x, x+8}: 2 (b,seg) combos
  const int b = bs & 3, sseg = bs >> 2;
  const int qblk = lin >> 4;        // 0..31 (256-q blocks)
  const int q0w = qblk * 256 + w * 32;
  const int m00 = sseg * KEYS_PER;

  // persistent Q^T B-frags: q = q0w + l31, d = c*16 + h*8 + j
  bf16x8 qf[3];
#pragma unroll
  for (int c = 0; c < 3; ++c)
    qf[c] = *(const bf16x8*)(Qb + ((size_t)b * NPTS + q0w + l31) * DQK +
                             c * 16 + h * 8);

  // V staging: wave w handles frags {2w, 2w+1} (16 total, uniform)
  const ushort_t* gp[2];
  int fid[2];
#pragma unroll
  for (int i = 0; i < 2; ++i) {
    int fi = w * 2 + i;
    fid[i] = fi;
    int fch = fi >> 2, kk = fi & 3;
    gp[i] = Vt + ((size_t)b * NCH + fch * 32 + l31) * NPTS + m00 + kk * 16 + h * 8;
  }

  // K direct-from-global (L2-resident): per-lane address of the A-fragment
  const ushort_t* kp = Kb + ((size_t)b * NPTS + m00 + l31) * DQK + h * 8;

  f32x16 O[4];
#pragma unroll
  for (int f = 0; f < 4; ++f) O[f] = (f32x16)(0.f);
  float ls0 = 0.f, ls1 = 0.f;

  // prologue: stage V round 0 into buffer 0
#pragma unroll
  for (int i = 0; i < 2; ++i) gload_lds16(gp[i], &L[0][fid[i]][0]);

#pragma unroll 1
  for (int t = 0; t < ROUNDS; ++t) {
    __syncthreads();  // vmcnt(0): buf[t&1] DMA (issued a full round ago) drained
    const int cur = t & 1;
    if (t + 1 < ROUNDS) {
#pragma unroll
      for (int i = 0; i < 2; ++i) {
        gp[i] += TK;
        gload_lds16(gp[i], &L[cur ^ 1][fid[i]][0]);  // overlaps compute below
      }
    }

#pragma unroll
    for (int kb = 0; kb < 2; ++kb) {
      // K fragment loads: global -> regs, L2-hit (~200cyc, hidden by 4 waves/SIMD)
      const ushort_t* kpb = kp + (size_t)kb * 32 * DQK;
      bf16x8 kf0 = *(const bf16x8*)(kpb);
      bf16x8 kf1 = *(const bf16x8*)(kpb + 16);
      bf16x8 kf2 = *(const bf16x8*)(kpb + 32);

      __builtin_amdgcn_s_setprio(1);
      f32x16 S = __builtin_amdgcn_mfma_f32_32x32x16_bf16(kf0, qf[0],
                                                         (f32x16)(0.f), 0, 0, 0);
      S = __builtin_amdgcn_mfma_f32_32x32x16_bf16(kf1, qf[1], S, 0, 0, 0);
      S = __builtin_amdgcn_mfma_f32_32x32x16_bf16(kf2, qf[2], S, 0, 0, 0);
      __builtin_amdgcn_s_setprio(0);

      // shift already folded into S via slot 35: p = exp2(S) directly
      uint_t pk[8];
#pragma unroll
      for (int i = 0; i < 8; ++i) {
        float p0 = __builtin_amdgcn_exp2f(S[2 * i]);
        float p1 = __builtin_amdgcn_exp2f(S[2 * i + 1]);
        ls0 += p0;
        ls1 += p1;
        pk[i] = __builtin_amdgcn_perm(__float_as_uint(p1), __float_as_uint(p0),
                                      0x07060302u);
      }

      // sigma16-permuted V => C-regs pack directly into PV A-frags
#pragma unroll
      for (int kkl = 0; kkl < 2; ++kkl) {
        union { uint_t u[4]; bf16x8 v; } au;
        au.u[0] = pk[4 * kkl + 0];
        au.u[1] = pk[4 * kkl + 1];
        au.u[2] = pk[4 * kkl + 2];
        au.u[3] = pk[4 * kkl + 3];
        bf16x8 A = au.v;
        __builtin_amdgcn_s_setprio(1);
#pragma unroll
        for (int f = 0; f < 4; ++f) {
          bf16x8 vf = *(const bf16x8*)(&L[cur][f * 4 + kb * 2 + kkl][0] + lane * 8);
          O[f] = __builtin_amdgcn_mfma_f32_32x32x16_bf16(A, vf, O[f], 0, 0, 0);
        }
        __builtin_amdgcn_s_setprio(0);
      }
    }
    kp += (size_t)TK * DQK;
  }

  // epilogue: same PACC layout (chunk = (qblk&1)*8 + w)
  float lsum = ls0 + ls1;
  lsum += __shfl_xor(lsum, 32);
  const size_t pbase = (size_t)(bs * 16 + (qblk >> 1)) * 16 + (qblk & 1) * 8 + w;
#pragma unroll
  for (int f = 0; f < 4; ++f) {
    union { ushort_t u[16]; bf16x8 v[2]; } pu;
#pragma unroll
    for (int r = 0; r < 16; ++r) pu.u[r] = f2bf(O[f][r]);
    size_t idx = (pbase * 4 + f) * 1024 + (size_t)lane * 16;
    *(bf16x8*)(PACC + idx) = pu.v[0];
    *(bf16x8*)(PACC + idx + 8) = pu.v[1];
  }
  if (lane < 32) PL[(size_t)bs * NPTS + q0w + lane] = lsum;
}

// ---------------------------------------------------------------------------
// Merge 4 key-split partials + gamma + x, COALESCED output via LDS bounce.
// grid (qblk2 32, b 4, f 4); each block: 256 q x 32 ch.
// Phase 1: coalesced PACC reads, sum over s, x Linv, stage fp32 in LDS.
// Phase 2: wave w -> 8 ch rows; lane -> q=lane*4: contiguous 1KB load/stores.
// ---------------------------------------------------------------------------
#define MPITCH 268
__global__ __launch_bounds__(256, 4)
void merge4c_kernel(const ushort_t* __restrict__ PACC, const float* __restrict__ PL,
                    const float* __restrict__ x, const float* __restrict__ gamma,
                    float* __restrict__ out) {
  __shared__ float Linv[256];
  __shared__ float ldso[32 * MPITCH];
  const int tid = threadIdx.x;
  const int qblk2 = blockIdx.x, b = blockIdx.y, f = blockIdx.z;
  const int q0 = qblk2 * 256;

  float Ls = 0.f;
#pragma unroll
  for (int s = 0; s < 4; ++s)
    Ls += PL[(size_t)(s * 4 + b) * NPTS + q0 + tid];
  Linv[tid] = gamma[0] / Ls;
  __syncthreads();

  const int ww = tid >> 6, lane = tid & 63, l31 = lane & 31, h = lane >> 5;

#pragma unroll
  for (int g = 0; g < 2; ++g) {
    float acc[16];
#pragma unroll
    for (int r = 0; r < 16; ++r) acc[r] = 0.f;
#pragma unroll
    for (int s = 0; s < 4; ++s) {
      size_t idx = (((((size_t)(s * 4 + b) * 16 + (qblk2 >> 1)) * 8 +
                      (qblk2 & 1) * 4 + ww) * 2 + g) * 4 + f) * 1024 +
                   (size_t)lane * 16;
      bf16x8 a0 = *(const bf16x8*)(PACC + idx);
      bf16x8 a1 = *(const bf16x8*)(PACC + idx + 8);
#pragma unroll
      for (int r = 0; r < 8; ++r) {
        acc[r] += bf2f((ushort_t)a0[r]);
        acc[8 + r] += bf2f((ushort_t)a1[r]);
      }
    }
    const int qb = ww * 64 + g * 32 + 4 * h;
#pragma unroll
    for (int rr = 0; rr < 4; ++rr) {
      int q = qb + 8 * rr;
      f32x4 v;
#pragma unroll
      for (int i = 0; i < 4; ++i) v[i] = acc[rr * 4 + i] * Linv[q + i];
      *(f32x4*)&ldso[l31 * MPITCH + q] = v;  // ch_local = l31
    }
  }
  __syncthreads();

  // phase 2: coalesced: wave ww -> ch rows ww*8..+7, lane -> q = lane*4
  const float* xb = x + ((size_t)b * NCH + f * 32) * NPTS + q0;
  float* ob = out + ((size_t)b * NCH + f * 32) * NPTS + q0;
#pragma unroll
  for (int rr = 0; rr < 8; ++rr) {
    int ch = ww * 8 + rr;
    f32x4 v = *(const f32x4*)&ldso[ch * MPITCH + lane * 4];
    f32x4 xv = *(const f32x4*)(xb + (size_t)ch * NPTS + lane * 4);
    v += xv;
    *(f32x4*)(ob + (size_t)ch * NPTS + lane * 4) = v;
  }
}

// ---------------------------------------------------------------------------
extern "C" void kernel_launch(void* const* d_in, const int* in_sizes, int n_in,
                              void* d_out, int out_size, void* d_ws,
                              size_t ws_size, hipStream_t stream) {
  const float* x     = (const float*)d_in[0];
  const float* xyz   = (const float*)d_in[1];
  const float* Wq    = (const float*)d_in[2];
  const float* bq    = (const float*)d_in[3];
  const float* Wk    = (const float*)d_in[4];
  const float* bk    = (const float*)d_in[5];
  const float* Wv    = (const float*)d_in[6];
  const float* bv    = (const float*)d_in[7];
  const float* gamma = (const float*)d_in[8];
  float* out = (float*)d_out;

  const size_t BN = (size_t)NB * NPTS;
  ushort_t* Qb = (ushort_t*)d_ws;
  ushort_t* Kb = Qb + BN * DQK;
  ushort_t* Vt = Kb + BN * DQK;
  ushort_t* PACC = Vt + BN * NCH;   // 16 bs * 16 qblk * 16 chunk * 4 f * 1024
  float* PL = (float*)(PACC + (size_t)16 * 16 * 8 * 2 * 4 * 1024);
  ushort_t* Wb = (ushort_t*)(PL + 16 * BN / 2);  // 6*8*64*8 = 24576 ushort
  float* bias_pre = (float*)(Wb + 6 * 8 * 64 * 8);

  wprep_kernel<<<6, 512, 0, stream>>>(Wq, bq, Wk, bk, Wv, bv, Wb, bias_pre);
  projm2_kernel<<<dim3(NPTS / 128, NB), 256, 0, stream>>>(
      x, xyz, Wb, bias_pre, Qb, Kb, Vt);
  attn32_kernel<<<512, 512, 0, stream>>>(Qb, Kb, Vt, PACC, PL);
  merge4c_kernel<<<dim3(32, NB, 4), 256, 0, stream>>>(PACC, PL, x, gamma, out);
  (void)in_sizes; (void)n_in; (void)out_size; (void)ws_size;
}

// Round 4
// 193.212 us; speedup vs baseline: 1.2421x; 1.0225x over previous
//
#include <hip/hip_runtime.h>

#define NPTS 8192
#define NB 4
#define NCH 128
#define DQK 48
#define TK 64
#define SPLIT 4
#define KEYS_PER (NPTS / SPLIT)   // 2048
#define ROUNDS (KEYS_PER / TK)    // 32
#define SH2 28.853901f            // 20 * log2(e)
#define LOG2E 1.4426950408889634f

typedef unsigned short ushort_t;
typedef unsigned int uint_t;
typedef __attribute__((ext_vector_type(8))) short bf16x8;
typedef __attribute__((ext_vector_type(4))) float f32x4;
typedef __attribute__((ext_vector_type(16))) float f32x16;

static __device__ __forceinline__ ushort_t f2bf(float x) {
  union { float f; uint_t u; } v; v.f = x;
  uint_t r = v.u + 0x7fffu + ((v.u >> 16) & 1u);
  return (ushort_t)(r >> 16);
}
static __device__ __forceinline__ float bf2f(ushort_t u) {
  union { uint_t i; float f; } v; v.i = ((uint_t)u) << 16; return v.f;
}
// sigma16: swap middle two 4-blocks of each 16-group (involution).
// Makes S^T C-layout regs directly usable as the PV A-fragment.
static __device__ __forceinline__ int sig16(int n) {
  int g2 = (n >> 2) & 3;
  return (g2 == 1 || g2 == 2) ? (n ^ 0xC) : n;
}

typedef __attribute__((address_space(1))) void void_g;
typedef __attribute__((address_space(3))) void void_l;
static __device__ __forceinline__ void gload_lds16(const ushort_t* g, ushort_t* l) {
  __builtin_amdgcn_global_load_lds((void_g*)(ushort_t*)g, (void_l*)l, 16, 0, 0);
}

// ---------------------------------------------------------------------------
// FRAGMENT-MAJOR intermediate layouts (R11):
//  Qb/Kb: [b][kblk = n>>5][c(3)][lane(64)][8]   (lane = (n&31) + 32*((d>>3)&1),
//         elem j = d&7, c = d>>4; d = 0..47, slots 32..47 hold xhat + shift)
//  Vt:    [b][mblk = np>>6][frag(16) = fch*4+kk][lane(64)][8]
//         (lane = (ch&31) + 32*((np>>3)&1), j = np&7; np = sig16-permuted key)
// All attn-side reads / staging DMA become lane-contiguous 1KB bursts
// (~8 L1 transactions per fragment instead of 24-64 with row-major).
// ---------------------------------------------------------------------------

// ---------------------------------------------------------------------------
// Weight prep: W -> A-fragment-ordered bf16 Wb[z][ks][lane][8] (log2e folded
// into z=0), plus fused scaled bias bias_pre[192]. 6 blocks, one z each.
// ---------------------------------------------------------------------------
__global__ __launch_bounds__(512, 1)
void wprep_kernel(const float* __restrict__ Wq, const float* __restrict__ bq,
                  const float* __restrict__ Wk, const float* __restrict__ bk,
                  const float* __restrict__ Wv, const float* __restrict__ bv,
                  ushort_t* __restrict__ Wb, float* __restrict__ bias_pre) {
  const int z = blockIdx.x;
  const int ks = threadIdx.x >> 6;
  const int lane = threadIdx.x & 63;
  const int l31 = lane & 31, h = lane >> 5;
  const float* W = (z == 0) ? Wq : (z == 1) ? Wk : (Wv + (size_t)(z - 2) * 32 * 128);
  const float sc = (z == 0) ? LOG2E : 1.0f;
  const float* wr = W + l31 * 128 + ks * 16 + h * 8;
  union { ushort_t u[8]; bf16x8 v; } p;
#pragma unroll
  for (int j = 0; j < 8; ++j) p.u[j] = f2bf(wr[j] * sc);
  *(bf16x8*)(Wb + ((size_t)(z * 8 + ks) * 64 + lane) * 8) = p.v;
  if (z == 0 && threadIdx.x < 192) {
    int i = threadIdx.x;
    bias_pre[i] = (i < 32) ? bq[i] * LOG2E : (i < 64) ? bk[i - 32] : bv[i - 64];
  }
}

// ---------------------------------------------------------------------------
// MFMA projections, fused over all 6 bands: x B-frags loaded+converted ONCE
// per wave (32 n-cols), reused for 48 MFMAs. A-frags from pre-packed Wb.
// C layout: col = lane&31, row = (r&3)+8*(r>>2)+4h.
// Outputs in FRAGMENT-MAJOR layouts (see above). Softmax shift folded into
// slot d=35: Q[35] = -SH2, K[35] = 1.0 => attn does exp2(S) with no subtract.
// ---------------------------------------------------------------------------
__global__ __launch_bounds__(256, 4)
void projm2_kernel(const float* __restrict__ x, const float* __restrict__ xyz,
                   const ushort_t* __restrict__ Wb,
                   const float* __restrict__ bias_pre,
                   ushort_t* __restrict__ Qb, ushort_t* __restrict__ Kb,
                   ushort_t* __restrict__ Vt) {
  const int tid = threadIdx.x;
  const int lane = tid & 63, wv = tid >> 6;
  const int l31 = lane & 31, h = lane >> 5;
  const int b = blockIdx.y;
  const int n = blockIdx.x * 128 + wv * 32 + l31;

  // B-frags from x (coalesced per c-row), converted once, reused 6x
  bf16x8 bfr[8];
  const float* xb = x + (size_t)b * NCH * NPTS + n;
#pragma unroll
  for (int ks = 0; ks < 8; ++ks) {
    const float* xc = xb + (size_t)(ks * 16 + h * 8) * NPTS;
    union { ushort_t u[8]; bf16x8 v; } p;
#pragma unroll
    for (int j = 0; j < 8; ++j) p.u[j] = f2bf(xc[(size_t)j * NPTS]);
    bfr[ks] = p.v;
  }

  // xhat (bands 0,1)
  float xa = xyz[((size_t)b * NPTS + n) * 3 + 0];
  float xc2 = xyz[((size_t)b * NPTS + n) * 3 + 1];
  float xd = xyz[((size_t)b * NPTS + n) * 3 + 2];
  float rinv = 1.0f / (sqrtf(xa * xa + xc2 * xc2 + xd * xd) + 1e-8f);

#pragma unroll 1
  for (int z = 0; z < 6; ++z) {
    f32x16 S;
#pragma unroll
    for (int r = 0; r < 16; ++r)
      S[r] = bias_pre[z * 32 + (r & 3) + 8 * (r >> 2) + 4 * h];
#pragma unroll
    for (int ks = 0; ks < 8; ++ks) {
      bf16x8 af = *(const bf16x8*)(Wb + ((size_t)(z * 8 + ks) * 64 + lane) * 8);
      S = __builtin_amdgcn_mfma_f32_32x32x16_bf16(af, bfr[ks], S, 0, 0, 0);
    }
    if (z <= 1) {
      // frag-major Q/K: base of this point's kblk
      ushort_t* dstf = (z == 0 ? Qb : Kb) +
                       (((size_t)b * 256 + (n >> 5)) * 3) * 512;
      const int lbase = l31 * 8;
      // S[r] -> d = (r&3) + 8*(r>>2) + 4h: c = r>>3, hbit = (r>>2)&1,
      // j = (r&3)+4h
#pragma unroll
      for (int r = 0; r < 16; ++r) {
        int idx = (r >> 3) * 512 + ((r >> 2) & 1) * 256 + lbase + (r & 3) + 4 * h;
        dstf[idx] = f2bf(S[r]);
      }
      float sc = (z == 0) ? LOG2E : 1.0f;
      float rn = 0.31622776601683794f * sc * rinv;
      union { ushort_t u[16]; bf16x8 v[2]; } t;
#pragma unroll
      for (int j = 0; j < 16; ++j) t.u[j] = 0;
      t.u[0] = f2bf(xa * rn); t.u[1] = f2bf(xc2 * rn); t.u[2] = f2bf(xd * rn);
      t.u[3] = (z == 0) ? f2bf(-SH2) : f2bf(1.0f);  // folded softmax shift (d=35)
      // c=2 frag: e=0..7 at +1024, e=8..15 at +1024+256
      *(bf16x8*)(dstf + 1024 + lbase) = t.v[0];
      *(bf16x8*)(dstf + 1024 + 256 + lbase) = t.v[1];
    } else {
      // frag-major V with sig16-permuted key position
      const int np = (n & ~15) | sig16(n & 15);
      const size_t base =
          (((size_t)b * 128 + (np >> 6)) * 16 + (z - 2) * 4 + ((np >> 4) & 3)) * 512 +
          ((np >> 3) & 1) * 256 + (np & 7);
#pragma unroll
      for (int r = 0; r < 16; ++r) {
        int dd = (r & 3) + 8 * (r >> 2) + 4 * h;   // ch within 32-group
        Vt[base + dd * 8] = f2bf(S[r]);
      }
    }
  }
}

// ---------------------------------------------------------------------------
// MFMA flash attention, 32x32x16, 32 q/wave, 8 waves = 256 q/block.
// R11 (post-mortem R10): R10's regression (103.7 vs R8's 91.2) was vmcnt
// IN-ORDER retirement: staging DMA issued BEFORE the K reg-loads meant the
// K-consume waitcnt (vmcnt(0)) drained the just-issued staging every round.
// FIX: per round, load kb0's K frags FIRST, then issue staging (K use ->
// vmcnt(2), staging stays in flight); kb1's K loads mid-round force vmcnt(0)
// but staging has had ~2500cyc by then -> free. Plus FRAGMENT-MAJOR Q/K/V
// (lane-contiguous 1KB bursts; kills the 24-64x L1 transaction amplification
// of the old row-major 96B/16KB lane strides).
// Pipes per CU-round: LDS 3010 (V only), MFMA 2841, VALU 2670, L2-K 1714.
// ---------------------------------------------------------------------------
__global__ __launch_bounds__(512, 4)
void attn32_kernel(const ushort_t* __restrict__ Qb, const ushort_t* __restrict__ Kb,
                   const ushort_t* __restrict__ Vt,
                   ushort_t* __restrict__ PACC, float* __restrict__ PL) {
  // V frags only: frag v = fch*4 + kk (16 total); each 64 lanes x 16B
  __shared__ __align__(16) ushort_t L[2][16][512];
  const int tid = threadIdx.x;
  const int lane = tid & 63, w = tid >> 6;
  const int l31 = lane & 31;

  const int lin = blockIdx.x;
  const int bs = lin & 15;          // XCD x sees bs in {x, x+8}: 2 (b,seg) combos
  const int b = bs & 3, sseg = bs >> 2;
  const int qblk = lin >> 4;        // 0..31 (256-q blocks)
  const int q0w = qblk * 256 + w * 32;
  const int m00 = sseg * KEYS_PER;

  // persistent Q^T B-frags (frag-major, lane-contiguous)
  bf16x8 qf[3];
  {
    const ushort_t* qbase = Qb + (((size_t)b * 256 + (q0w >> 5)) * 3) * 512 + lane * 8;
#pragma unroll
    for (int c = 0; c < 3; ++c) qf[c] = *(const bf16x8*)(qbase + c * 512);
  }

  // K direct-from-global (L2-resident), frag-major
  const ushort_t* kbase = Kb + (((size_t)b * 256 + (m00 >> 5)) * 3) * 512 + lane * 8;
  // V staging source, frag-major; wave w stages frags {2w, 2w+1}
  const ushort_t* vsrc = Vt + (((size_t)b * 128 + (m00 >> 6)) * 16) * 512 + lane * 8;
  const int f0 = 2 * w, f1 = 2 * w + 1;

  f32x16 O[4];
#pragma unroll
  for (int f = 0; f < 4; ++f) O[f] = (f32x16)(0.f);
  float ls0 = 0.f, ls1 = 0.f;

  // prologue: stage V round 0 into buffer 0
  gload_lds16(vsrc + f0 * 512, &L[0][f0][0]);
  gload_lds16(vsrc + f1 * 512, &L[0][f1][0]);

#pragma unroll 1
  for (int t = 0; t < ROUNDS; ++t) {
    __syncthreads();  // vmcnt(0): buf[t&1] DMA (issued a full round ago) drained
    const int cur = t & 1;

    // ---- kb0 K loads FIRST (so staging below is NOT drained by their use)
    bf16x8 ka0 = *(const bf16x8*)(kbase);
    bf16x8 ka1 = *(const bf16x8*)(kbase + 512);
    bf16x8 ka2 = *(const bf16x8*)(kbase + 1024);

    // ---- issue next-round V staging (in flight across the whole round)
    if (t + 1 < ROUNDS) {
      vsrc += 16 * 512;
      gload_lds16(vsrc + f0 * 512, &L[cur ^ 1][f0][0]);
      gload_lds16(vsrc + f1 * 512, &L[cur ^ 1][f1][0]);
    }

#pragma unroll
    for (int kb = 0; kb < 2; ++kb) {
      bf16x8 kf0, kf1, kf2;
      if (kb == 0) {
        kf0 = ka0; kf1 = ka1; kf2 = ka2;
      } else {
        // kb1 loads: vmcnt(0) at their use is fine - staging issued
        // ~2500 cyc earlier has already retired.
        kf0 = *(const bf16x8*)(kbase + 1536);
        kf1 = *(const bf16x8*)(kbase + 2048);
        kf2 = *(const bf16x8*)(kbase + 2560);
      }

      __builtin_amdgcn_s_setprio(1);
      f32x16 S = __builtin_amdgcn_mfma_f32_32x32x16_bf16(kf0, qf[0],
                                                         (f32x16)(0.f), 0, 0, 0);
      S = __builtin_amdgcn_mfma_f32_32x32x16_bf16(kf1, qf[1], S, 0, 0, 0);
      S = __builtin_amdgcn_mfma_f32_32x32x16_bf16(kf2, qf[2], S, 0, 0, 0);
      __builtin_amdgcn_s_setprio(0);

      // shift already folded into S via slot 35: p = exp2(S) directly
      uint_t pk[8];
#pragma unroll
      for (int i = 0; i < 8; ++i) {
        float p0 = __builtin_amdgcn_exp2f(S[2 * i]);
        float p1 = __builtin_amdgcn_exp2f(S[2 * i + 1]);
        ls0 += p0;
        ls1 += p1;
        pk[i] = __builtin_amdgcn_perm(__float_as_uint(p1), __float_as_uint(p0),
                                      0x07060302u);
      }

      // sigma16-permuted V => C-regs pack directly into PV A-frags
#pragma unroll
      for (int kkl = 0; kkl < 2; ++kkl) {
        union { uint_t u[4]; bf16x8 v; } au;
        au.u[0] = pk[4 * kkl + 0];
        au.u[1] = pk[4 * kkl + 1];
        au.u[2] = pk[4 * kkl + 2];
        au.u[3] = pk[4 * kkl + 3];
        bf16x8 A = au.v;
        __builtin_amdgcn_s_setprio(1);
#pragma unroll
        for (int f = 0; f < 4; ++f) {
          bf16x8 vf = *(const bf16x8*)(&L[cur][f * 4 + kb * 2 + kkl][0] + lane * 8);
          O[f] = __builtin_amdgcn_mfma_f32_32x32x16_bf16(A, vf, O[f], 0, 0, 0);
        }
        __builtin_amdgcn_s_setprio(0);
      }
    }
    kbase += 3072;
  }

  // epilogue: same PACC layout (chunk = (qblk&1)*8 + w)
  float lsum = ls0 + ls1;
  lsum += __shfl_xor(lsum, 32);
  const size_t pbase = (size_t)(bs * 16 + (qblk >> 1)) * 16 + (qblk & 1) * 8 + w;
#pragma unroll
  for (int f = 0; f < 4; ++f) {
    union { ushort_t u[16]; bf16x8 v[2]; } pu;
#pragma unroll
    for (int r = 0; r < 16; ++r) pu.u[r] = f2bf(O[f][r]);
    size_t idx = (pbase * 4 + f) * 1024 + (size_t)lane * 16;
    *(bf16x8*)(PACC + idx) = pu.v[0];
    *(bf16x8*)(PACC + idx + 8) = pu.v[1];
  }
  if (lane < 32) PL[(size_t)bs * NPTS + q0w + lane] = lsum;
}

// ---------------------------------------------------------------------------
// Merge 4 key-split partials + gamma + x, COALESCED output via LDS bounce.
// grid (qblk2 32, b 4, f 4); each block: 256 q x 32 ch.
// Phase 1: coalesced PACC reads, sum over s, x Linv, stage fp32 in LDS.
// Phase 2: wave w -> 8 ch rows; lane -> q=lane*4: contiguous 1KB load/stores.
// ---------------------------------------------------------------------------
#define MPITCH 268
__global__ __launch_bounds__(256, 4)
void merge4c_kernel(const ushort_t* __restrict__ PACC, const float* __restrict__ PL,
                    const float* __restrict__ x, const float* __restrict__ gamma,
                    float* __restrict__ out) {
  __shared__ float Linv[256];
  __shared__ float ldso[32 * MPITCH];
  const int tid = threadIdx.x;
  const int qblk2 = blockIdx.x, b = blockIdx.y, f = blockIdx.z;
  const int q0 = qblk2 * 256;

  float Ls = 0.f;
#pragma unroll
  for (int s = 0; s < 4; ++s)
    Ls += PL[(size_t)(s * 4 + b) * NPTS + q0 + tid];
  Linv[tid] = gamma[0] / Ls;
  __syncthreads();

  const int ww = tid >> 6, lane = tid & 63, l31 = lane & 31, h = lane >> 5;

#pragma unroll
  for (int g = 0; g < 2; ++g) {
    float acc[16];
#pragma unroll
    for (int r = 0; r < 16; ++r) acc[r] = 0.f;
#pragma unroll
    for (int s = 0; s < 4; ++s) {
      size_t idx = (((((size_t)(s * 4 + b) * 16 + (qblk2 >> 1)) * 8 +
                      (qblk2 & 1) * 4 + ww) * 2 + g) * 4 + f) * 1024 +
                   (size_t)lane * 16;
      bf16x8 a0 = *(const bf16x8*)(PACC + idx);
      bf16x8 a1 = *(const bf16x8*)(PACC + idx + 8);
#pragma unroll
      for (int r = 0; r < 8; ++r) {
        acc[r] += bf2f((ushort_t)a0[r]);
        acc[8 + r] += bf2f((ushort_t)a1[r]);
      }
    }
    const int qb = ww * 64 + g * 32 + 4 * h;
#pragma unroll
    for (int rr = 0; rr < 4; ++rr) {
      int q = qb + 8 * rr;
      f32x4 v;
#pragma unroll
      for (int i = 0; i < 4; ++i) v[i] = acc[rr * 4 + i] * Linv[q + i];
      *(f32x4*)&ldso[l31 * MPITCH + q] = v;  // ch_local = l31
    }
  }
  __syncthreads();

  // phase 2: coalesced: wave ww -> ch rows ww*8..+7, lane -> q = lane*4
  const float* xb = x + ((size_t)b * NCH + f * 32) * NPTS + q0;
  float* ob = out + ((size_t)b * NCH + f * 32) * NPTS + q0;
#pragma unroll
  for (int rr = 0; rr < 8; ++rr) {
    int ch = ww * 8 + rr;
    f32x4 v = *(const f32x4*)&ldso[ch * MPITCH + lane * 4];
    f32x4 xv = *(const f32x4*)(xb + (size_t)ch * NPTS + lane * 4);
    v += xv;
    *(f32x4*)(ob + (size_t)ch * NPTS + lane * 4) = v;
  }
}

// ---------------------------------------------------------------------------
extern "C" void kernel_launch(void* const* d_in, const int* in_sizes, int n_in,
                              void* d_out, int out_size, void* d_ws,
                              size_t ws_size, hipStream_t stream) {
  const float* x     = (const float*)d_in[0];
  const float* xyz   = (const float*)d_in[1];
  const float* Wq    = (const float*)d_in[2];
  const float* bq    = (const float*)d_in[3];
  const float* Wk    = (const float*)d_in[4];
  const float* bk    = (const float*)d_in[5];
  const float* Wv    = (const float*)d_in[6];
  const float* bv    = (const float*)d_in[7];
  const float* gamma = (const float*)d_in[8];
  float* out = (float*)d_out;

  const size_t BN = (size_t)NB * NPTS;
  ushort_t* Qb = (ushort_t*)d_ws;                 // 4*256*3*512 = BN*DQK
  ushort_t* Kb = Qb + BN * DQK;
  ushort_t* Vt = Kb + BN * DQK;                   // 4*128*16*512 = BN*NCH
  ushort_t* PACC = Vt + BN * NCH;   // 16 bs * 16 qblk * 16 chunk * 4 f * 1024
  float* PL = (float*)(PACC + (size_t)16 * 16 * 8 * 2 * 4 * 1024);
  ushort_t* Wb = (ushort_t*)(PL + 16 * BN / 2);  // 6*8*64*8 = 24576 ushort
  float* bias_pre = (float*)(Wb + 6 * 8 * 64 * 8);

  wprep_kernel<<<6, 512, 0, stream>>>(Wq, bq, Wk, bk, Wv, bv, Wb, bias_pre);
  projm2_kernel<<<dim3(NPTS / 128, NB), 256, 0, stream>>>(
      x, xyz, Wb, bias_pre, Qb, Kb, Vt);
  attn32_kernel<<<512, 512, 0, stream>>>(Qb, Kb, Vt, PACC, PL);
  merge4c_kernel<<<dim3(32, NB, 4), 256, 0, stream>>>(PACC, PL, x, gamma, out);
  (void)in_sizes; (void)n_in; (void)out_size; (void)ws_size;
}

// Round 5
// 189.182 us; speedup vs baseline: 1.2686x; 1.0213x over previous
//
#include <hip/hip_runtime.h>

#define NPTS 8192
#define NB 4
#define NCH 128
#define DQK 48
#define TK 64
#define SPLIT 4
#define KEYS_PER (NPTS / SPLIT)   // 2048
#define ROUNDS (KEYS_PER / TK)    // 32
#define SH2 28.853901f            // 20 * log2(e)
#define LOG2E 1.4426950408889634f

typedef unsigned short ushort_t;
typedef unsigned int uint_t;
typedef __attribute__((ext_vector_type(8))) short bf16x8;
typedef __attribute__((ext_vector_type(4))) float f32x4;
typedef __attribute__((ext_vector_type(16))) float f32x16;

static __device__ __forceinline__ ushort_t f2bf(float x) {
  union { float f; uint_t u; } v; v.f = x;
  uint_t r = v.u + 0x7fffu + ((v.u >> 16) & 1u);
  return (ushort_t)(r >> 16);
}
static __device__ __forceinline__ float bf2f(ushort_t u) {
  union { uint_t i; float f; } v; v.i = ((uint_t)u) << 16; return v.f;
}
// sigma16: swap middle two 4-blocks of each 16-group (involution).
// Makes S^T C-layout regs directly usable as the PV A-fragment.
static __device__ __forceinline__ int sig16(int n) {
  int g2 = (n >> 2) & 3;
  return (g2 == 1 || g2 == 2) ? (n ^ 0xC) : n;
}

typedef __attribute__((address_space(1))) void void_g;
typedef __attribute__((address_space(3))) void void_l;
static __device__ __forceinline__ void gload_lds16(const ushort_t* g, ushort_t* l) {
  __builtin_amdgcn_global_load_lds((void_g*)(ushort_t*)g, (void_l*)l, 16, 0, 0);
}

// ---------------------------------------------------------------------------
// FRAGMENT-MAJOR intermediate layouts:
//  Qb/Kb: [b][kblk = n>>5][c(3)][lane(64)][8]   (lane = (n&31) + 32*((d>>3)&1),
//         elem j = d&7, c = d>>4; d = 0..47, slots 32..47 hold xhat + shift)
//  Vt:    [b][mblk = np>>6][frag(16) = fch*4+kk][lane(64)][8]
//         (lane = (ch&31) + 32*((np>>3)&1), j = np&7; np = sig16-permuted key)
// All attn-side staging DMA sources are lane-contiguous 1KB bursts.
// ---------------------------------------------------------------------------

// ---------------------------------------------------------------------------
// Weight prep: W -> A-fragment-ordered bf16 Wb[z][ks][lane][8] (log2e folded
// into z=0), plus fused scaled bias bias_pre[192]. 6 blocks, one z each.
// ---------------------------------------------------------------------------
__global__ __launch_bounds__(512, 1)
void wprep_kernel(const float* __restrict__ Wq, const float* __restrict__ bq,
                  const float* __restrict__ Wk, const float* __restrict__ bk,
                  const float* __restrict__ Wv, const float* __restrict__ bv,
                  ushort_t* __restrict__ Wb, float* __restrict__ bias_pre) {
  const int z = blockIdx.x;
  const int ks = threadIdx.x >> 6;
  const int lane = threadIdx.x & 63;
  const int l31 = lane & 31, h = lane >> 5;
  const float* W = (z == 0) ? Wq : (z == 1) ? Wk : (Wv + (size_t)(z - 2) * 32 * 128);
  const float sc = (z == 0) ? LOG2E : 1.0f;
  const float* wr = W + l31 * 128 + ks * 16 + h * 8;
  union { ushort_t u[8]; bf16x8 v; } p;
#pragma unroll
  for (int j = 0; j < 8; ++j) p.u[j] = f2bf(wr[j] * sc);
  *(bf16x8*)(Wb + ((size_t)(z * 8 + ks) * 64 + lane) * 8) = p.v;
  if (z == 0 && threadIdx.x < 192) {
    int i = threadIdx.x;
    bias_pre[i] = (i < 32) ? bq[i] * LOG2E : (i < 64) ? bk[i - 32] : bv[i - 64];
  }
}

// ---------------------------------------------------------------------------
// MFMA projections, fused over all 6 bands. R12: COALESCED STORE PATH.
// Old path wrote Q/K/V via ~16 scalar 2B scattered stores per band per wave
// (8-16x write-transaction amplification on 15MB of intermediates). New path:
// per band, 16 conflict-free ds_write_b16 into a padded 32x40 LDS tile
// (transpose n<->d / n<->ch), then 2 ds_read_b128 + 2 fully-coalesced 16B
// global stores (one complete 1KB fragment per store instruction).
// Softmax shift folded into slot d=35: Q[35]=-SH2, K[35]=1.0 (uniform per-row
// additive constant -> cancels in O/L normalization) => attn exp2's directly.
// ---------------------------------------------------------------------------
#define TPITCH 40   // ushorts; 80B rows: 16B-aligned b128 reads, 2-way banks (free)
__global__ __launch_bounds__(256, 4)
void projm2_kernel(const float* __restrict__ x, const float* __restrict__ xyz,
                   const ushort_t* __restrict__ Wb,
                   const float* __restrict__ bias_pre,
                   ushort_t* __restrict__ Qb, ushort_t* __restrict__ Kb,
                   ushort_t* __restrict__ Vt) {
  __shared__ __align__(16) ushort_t T[4][32 * TPITCH];
  const int tid = threadIdx.x;
  const int lane = tid & 63, wv = tid >> 6;
  const int l31 = lane & 31, h = lane >> 5;
  const int b = blockIdx.y;
  const int n0 = blockIdx.x * 128 + wv * 32;
  const int n = n0 + l31;

  // B-frags from x (coalesced per c-row), converted once, reused 6x
  bf16x8 bfr[8];
  const float* xb = x + (size_t)b * NCH * NPTS + n;
#pragma unroll
  for (int ks = 0; ks < 8; ++ks) {
    const float* xc = xb + (size_t)(ks * 16 + h * 8) * NPTS;
    union { ushort_t u[8]; bf16x8 v; } p;
#pragma unroll
    for (int j = 0; j < 8; ++j) p.u[j] = f2bf(xc[(size_t)j * NPTS]);
    bfr[ks] = p.v;
  }

  // xhat (bands 0,1)
  float xa = xyz[((size_t)b * NPTS + n) * 3 + 0];
  float xc2 = xyz[((size_t)b * NPTS + n) * 3 + 1];
  float xd = xyz[((size_t)b * NPTS + n) * 3 + 2];
  float rinv = 1.0f / (sqrtf(xa * xa + xc2 * xc2 + xd * xd) + 1e-8f);

  const int nploc = (l31 & 16) | sig16(l31 & 15);  // V key position within tile
  ushort_t* tw = &T[wv][0];

#pragma unroll 1
  for (int z = 0; z < 6; ++z) {
    f32x16 S;
#pragma unroll
    for (int r = 0; r < 16; ++r)
      S[r] = bias_pre[z * 32 + (r & 3) + 8 * (r >> 2) + 4 * h];
#pragma unroll
    for (int ks = 0; ks < 8; ++ks) {
      bf16x8 af = *(const bf16x8*)(Wb + ((size_t)(z * 8 + ks) * 64 + lane) * 8);
      S = __builtin_amdgcn_mfma_f32_32x32x16_bf16(af, bfr[ks], S, 0, 0, 0);
    }
    if (z <= 1) {
      // LDS tile [n31][d]: lane holds col n=l31, rows d=(r&3)+8*(r>>2)+4h
#pragma unroll
      for (int r = 0; r < 16; ++r)
        tw[l31 * TPITCH + (r & 3) + 8 * (r >> 2) + 4 * h] = f2bf(S[r]);
      ushort_t* dstf = (z == 0 ? Qb : Kb) +
                       (((size_t)b * 256 + (n0 >> 5)) * 3) * 512;
      // c=0,1 frags: lane = n31 + 32*hb, 8 consecutive d -> 16B read + store
#pragma unroll
      for (int c = 0; c < 2; ++c) {
        bf16x8 fr = *(const bf16x8*)&tw[(lane & 31) * TPITCH + c * 16 + (lane >> 5) * 8];
        *(bf16x8*)(dstf + c * 512 + lane * 8) = fr;
      }
      // c=2 frag: xhat + folded shift, register-direct (already frag-ordered)
      float sc = (z == 0) ? LOG2E : 1.0f;
      float rn = 0.31622776601683794f * sc * rinv;
      union { ushort_t u[16]; bf16x8 v[2]; } t;
#pragma unroll
      for (int j = 0; j < 16; ++j) t.u[j] = 0;
      t.u[0] = f2bf(xa * rn); t.u[1] = f2bf(xc2 * rn); t.u[2] = f2bf(xd * rn);
      t.u[3] = (z == 0) ? f2bf(-SH2) : f2bf(1.0f);  // folded softmax shift (d=35)
      *(bf16x8*)(dstf + 1024 + l31 * 8) = t.v[0];
      *(bf16x8*)(dstf + 1024 + 256 + l31 * 8) = t.v[1];
    } else {
      // LDS tile [ch31][nploc]: transpose n<->ch with sig16 folded in
#pragma unroll
      for (int r = 0; r < 16; ++r)
        tw[((r & 3) + 8 * (r >> 2) + 4 * h) * TPITCH + nploc] = f2bf(S[r]);
      // two complete fragments (16 keys x 32 ch each): coalesced 1KB stores
#pragma unroll
      for (int g = 0; g < 2; ++g) {
        bf16x8 fr = *(const bf16x8*)&tw[(lane & 31) * TPITCH + g * 16 + (lane >> 5) * 8];
        int kk = ((n0 >> 4) + g) & 3;
        ushort_t* dst = Vt + ((((size_t)b * 128 + (n0 >> 6)) * 16 +
                               (z - 2) * 4 + kk) * 512);
        *(bf16x8*)(dst + lane * 8) = fr;
      }
    }
  }
}

// ---------------------------------------------------------------------------
// MFMA flash attention, 32x32x16, 32 q/wave, 8 waves = 256 q/block.
// R12 (post-mortem R10/R11): K-from-L2 in the loop (R10/R11) stayed above
// R8's 91.2us despite a lower LDS pipe - per-use VMEM latency/waitcnt
// coupling costs more than LDS-staged K (issued a round ahead, drained free
// at the barrier). RESTORE R8's all-LDS 22-frag staging, now with frag-major
// sources: every DMA reads a lane-contiguous 1KB burst (R8's V source was a
// 16KB/lane stride = ~4x L2 overfetch; K ~3x). Same 2-buffer/1-barrier
// structure, ~64 arch + 64 acc regs -> 4 waves/SIMD.
// ---------------------------------------------------------------------------
__global__ __launch_bounds__(512, 4)
void attn32_kernel(const ushort_t* __restrict__ Qb, const ushort_t* __restrict__ Kb,
                   const ushort_t* __restrict__ Vt,
                   ushort_t* __restrict__ PACC, float* __restrict__ PL) {
  // frag f: V = fch*4+kk (0..15), K = 16 + kb*3 + c (16..21); 64 lanes x 16B
  __shared__ __align__(16) ushort_t L[2][22][512];
  const int tid = threadIdx.x;
  const int lane = tid & 63, w = tid >> 6;

  const int lin = blockIdx.x;
  const int bs = lin & 15;          // XCD x sees bs in {x, x+8}: 2 (b,seg) combos
  const int b = bs & 3, sseg = bs >> 2;
  const int qblk = lin >> 4;        // 0..31 (256-q blocks)
  const int q0w = qblk * 256 + w * 32;
  const int m00 = sseg * KEYS_PER;

  // persistent Q^T B-frags (frag-major, lane-contiguous)
  bf16x8 qf[3];
  {
    const ushort_t* qbase = Qb + (((size_t)b * 256 + (q0w >> 5)) * 3) * 512 + lane * 8;
#pragma unroll
    for (int c = 0; c < 3; ++c) qf[c] = *(const bf16x8*)(qbase + c * 512);
  }

  // staging sources (frag-major, lane-contiguous): wave w -> frags {w,w+8,w+16}
  const ushort_t* vbase = Vt + (((size_t)b * 128 + (m00 >> 6)) * 16) * 512 + lane * 8;
  const ushort_t* kbase = Kb + (((size_t)b * 256 + (m00 >> 5)) * 3) * 512 + lane * 8;
  const ushort_t* gp[3];
  int fid[3], adv[3];
  const int nf = (w < 6) ? 3 : 2;
#pragma unroll
  for (int i = 0; i < 3; ++i) {
    int fi = w + 8 * i;
    fid[i] = fi;
    if (fi < 16) { gp[i] = vbase + fi * 512; adv[i] = 16 * 512; }
    else if (fi < 22) { gp[i] = kbase + (fi - 16) * 512; adv[i] = 6 * 512; }
  }

  f32x16 O[4];
#pragma unroll
  for (int f = 0; f < 4; ++f) O[f] = (f32x16)(0.f);
  float ls0 = 0.f, ls1 = 0.f;

  // prologue: stage round 0 into buffer 0
#pragma unroll
  for (int i = 0; i < 3; ++i)
    if (i < nf) gload_lds16(gp[i], &L[0][fid[i]][0]);

#pragma unroll 1
  for (int t = 0; t < ROUNDS; ++t) {
    __syncthreads();  // vmcnt(0): buf[t&1] DMA (issued a full round ago) drained
    const int cur = t & 1;
    if (t + 1 < ROUNDS) {
#pragma unroll
      for (int i = 0; i < 3; ++i)
        if (i < nf) {
          gp[i] += adv[i];
          gload_lds16(gp[i], &L[cur ^ 1][fid[i]][0]);  // overlaps compute below
        }
    }

#pragma unroll
    for (int kb = 0; kb < 2; ++kb) {
      bf16x8 kf0 = *(const bf16x8*)(&L[cur][16 + kb * 3 + 0][0] + lane * 8);
      bf16x8 kf1 = *(const bf16x8*)(&L[cur][16 + kb * 3 + 1][0] + lane * 8);
      bf16x8 kf2 = *(const bf16x8*)(&L[cur][16 + kb * 3 + 2][0] + lane * 8);

      __builtin_amdgcn_s_setprio(1);
      f32x16 S = __builtin_amdgcn_mfma_f32_32x32x16_bf16(kf0, qf[0],
                                                         (f32x16)(0.f), 0, 0, 0);
      S = __builtin_amdgcn_mfma_f32_32x32x16_bf16(kf1, qf[1], S, 0, 0, 0);
      S = __builtin_amdgcn_mfma_f32_32x32x16_bf16(kf2, qf[2], S, 0, 0, 0);
      __builtin_amdgcn_s_setprio(0);

      // shift already folded into S via slot 35: p = exp2(S) directly
      uint_t pk[8];
#pragma unroll
      for (int i = 0; i < 8; ++i) {
        float p0 = __builtin_amdgcn_exp2f(S[2 * i]);
        float p1 = __builtin_amdgcn_exp2f(S[2 * i + 1]);
        ls0 += p0;
        ls1 += p1;
        pk[i] = __builtin_amdgcn_perm(__float_as_uint(p1), __float_as_uint(p0),
                                      0x07060302u);
      }

      // sigma16-permuted V => C-regs pack directly into PV A-frags
#pragma unroll
      for (int kkl = 0; kkl < 2; ++kkl) {
        union { uint_t u[4]; bf16x8 v; } au;
        au.u[0] = pk[4 * kkl + 0];
        au.u[1] = pk[4 * kkl + 1];
        au.u[2] = pk[4 * kkl + 2];
        au.u[3] = pk[4 * kkl + 3];
        bf16x8 A = au.v;
        __builtin_amdgcn_s_setprio(1);
#pragma unroll
        for (int f = 0; f < 4; ++f) {
          bf16x8 vf = *(const bf16x8*)(&L[cur][f * 4 + kb * 2 + kkl][0] + lane * 8);
          O[f] = __builtin_amdgcn_mfma_f32_32x32x16_bf16(A, vf, O[f], 0, 0, 0);
        }
        __builtin_amdgcn_s_setprio(0);
      }
    }
  }

  // epilogue: same PACC layout (chunk = (qblk&1)*8 + w)
  float lsum = ls0 + ls1;
  lsum += __shfl_xor(lsum, 32);
  const size_t pbase = (size_t)(bs * 16 + (qblk >> 1)) * 16 + (qblk & 1) * 8 + w;
#pragma unroll
  for (int f = 0; f < 4; ++f) {
    union { ushort_t u[16]; bf16x8 v[2]; } pu;
#pragma unroll
    for (int r = 0; r < 16; ++r) pu.u[r] = f2bf(O[f][r]);
    size_t idx = (pbase * 4 + f) * 1024 + (size_t)lane * 16;
    *(bf16x8*)(PACC + idx) = pu.v[0];
    *(bf16x8*)(PACC + idx + 8) = pu.v[1];
  }
  if (lane < 32) PL[(size_t)bs * NPTS + q0w + lane] = lsum;
}

// ---------------------------------------------------------------------------
// Merge 4 key-split partials + gamma + x, COALESCED output via LDS bounce.
// grid (qblk2 32, b 4, f 4); each block: 256 q x 32 ch.
// Phase 1: coalesced PACC reads, sum over s, x Linv, stage fp32 in LDS.
// Phase 2: wave w -> 8 ch rows; lane -> q=lane*4: contiguous 1KB load/stores.
// ---------------------------------------------------------------------------
#define MPITCH 268
__global__ __launch_bounds__(256, 4)
void merge4c_kernel(const ushort_t* __restrict__ PACC, const float* __restrict__ PL,
                    const float* __restrict__ x, const float* __restrict__ gamma,
                    float* __restrict__ out) {
  __shared__ float Linv[256];
  __shared__ float ldso[32 * MPITCH];
  const int tid = threadIdx.x;
  const int qblk2 = blockIdx.x, b = blockIdx.y, f = blockIdx.z;
  const int q0 = qblk2 * 256;

  float Ls = 0.f;
#pragma unroll
  for (int s = 0; s < 4; ++s)
    Ls += PL[(size_t)(s * 4 + b) * NPTS + q0 + tid];
  Linv[tid] = gamma[0] / Ls;
  __syncthreads();

  const int ww = tid >> 6, lane = tid & 63, l31 = lane & 31, h = lane >> 5;

#pragma unroll
  for (int g = 0; g < 2; ++g) {
    float acc[16];
#pragma unroll
    for (int r = 0; r < 16; ++r) acc[r] = 0.f;
#pragma unroll
    for (int s = 0; s < 4; ++s) {
      size_t idx = (((((size_t)(s * 4 + b) * 16 + (qblk2 >> 1)) * 8 +
                      (qblk2 & 1) * 4 + ww) * 2 + g) * 4 + f) * 1024 +
                   (size_t)lane * 16;
      bf16x8 a0 = *(const bf16x8*)(PACC + idx);
      bf16x8 a1 = *(const bf16x8*)(PACC + idx + 8);
#pragma unroll
      for (int r = 0; r < 8; ++r) {
        acc[r] += bf2f((ushort_t)a0[r]);
        acc[8 + r] += bf2f((ushort_t)a1[r]);
      }
    }
    const int qb = ww * 64 + g * 32 + 4 * h;
#pragma unroll
    for (int rr = 0; rr < 4; ++rr) {
      int q = qb + 8 * rr;
      f32x4 v;
#pragma unroll
      for (int i = 0; i < 4; ++i) v[i] = acc[rr * 4 + i] * Linv[q + i];
      *(f32x4*)&ldso[l31 * MPITCH + q] = v;  // ch_local = l31
    }
  }
  __syncthreads();

  // phase 2: coalesced: wave ww -> ch rows ww*8..+7, lane -> q = lane*4
  const float* xb = x + ((size_t)b * NCH + f * 32) * NPTS + q0;
  float* ob = out + ((size_t)b * NCH + f * 32) * NPTS + q0;
#pragma unroll
  for (int rr = 0; rr < 8; ++rr) {
    int ch = ww * 8 + rr;
    f32x4 v = *(const f32x4*)&ldso[ch * MPITCH + lane * 4];
    f32x4 xv = *(const f32x4*)(xb + (size_t)ch * NPTS + lane * 4);
    v += xv;
    *(f32x4*)(ob + (size_t)ch * NPTS + lane * 4) = v;
  }
}

// ---------------------------------------------------------------------------
extern "C" void kernel_launch(void* const* d_in, const int* in_sizes, int n_in,
                              void* d_out, int out_size, void* d_ws,
                              size_t ws_size, hipStream_t stream) {
  const float* x     = (const float*)d_in[0];
  const float* xyz   = (const float*)d_in[1];
  const float* Wq    = (const float*)d_in[2];
  const float* bq    = (const float*)d_in[3];
  const float* Wk    = (const float*)d_in[4];
  const float* bk    = (const float*)d_in[5];
  const float* Wv    = (const float*)d_in[6];
  const float* bv    = (const float*)d_in[7];
  const float* gamma = (const float*)d_in[8];
  float* out = (float*)d_out;

  const size_t BN = (size_t)NB * NPTS;
  ushort_t* Qb = (ushort_t*)d_ws;                 // 4*256*3*512 = BN*DQK
  ushort_t* Kb = Qb + BN * DQK;
  ushort_t* Vt = Kb + BN * DQK;                   // 4*128*16*512 = BN*NCH
  ushort_t* PACC = Vt + BN * NCH;   // 16 bs * 16 qblk * 16 chunk * 4 f * 1024
  float* PL = (float*)(PACC + (size_t)16 * 16 * 8 * 2 * 4 * 1024);
  ushort_t* Wb = (ushort_t*)(PL + 16 * BN / 2);  // 6*8*64*8 = 24576 ushort
  float* bias_pre = (float*)(Wb + 6 * 8 * 64 * 8);

  wprep_kernel<<<6, 512, 0, stream>>>(Wq, bq, Wk, bk, Wv, bv, Wb, bias_pre);
  projm2_kernel<<<dim3(NPTS / 128, NB), 256, 0, stream>>>(
      x, xyz, Wb, bias_pre, Qb, Kb, Vt);
  attn32_kernel<<<512, 512, 0, stream>>>(Qb, Kb, Vt, PACC, PL);
  merge4c_kernel<<<dim3(32, NB, 4), 256, 0, stream>>>(PACC, PL, x, gamma, out);
  (void)in_sizes; (void)n_in; (void)out_size; (void)ws_size;
}

// Round 6
// 184.909 us; speedup vs baseline: 1.2979x; 1.0231x over previous
//
#include <hip/hip_runtime.h>

#define NPTS 8192
#define NB 4
#define NCH 128
#define DQK 48
#define TK 64
#define SPLIT 4
#define KEYS_PER (NPTS / SPLIT)   // 2048
#define ROUNDS (KEYS_PER / TK)    // 32
#define SH2 28.853901f            // 20 * log2(e)
#define LOG2E 1.4426950408889634f

typedef unsigned short ushort_t;
typedef unsigned int uint_t;
typedef __attribute__((ext_vector_type(8))) short bf16x8;
typedef __attribute__((ext_vector_type(2))) float f32x2;
typedef __attribute__((ext_vector_type(4))) float f32x4;
typedef __attribute__((ext_vector_type(16))) float f32x16;

static __device__ __forceinline__ ushort_t f2bf(float x) {
  union { float f; uint_t u; } v; v.f = x;
  uint_t r = v.u + 0x7fffu + ((v.u >> 16) & 1u);
  return (ushort_t)(r >> 16);
}
static __device__ __forceinline__ float bf2f(ushort_t u) {
  union { uint_t i; float f; } v; v.i = ((uint_t)u) << 16; return v.f;
}
// sigma16: swap middle two 4-blocks of each 16-group (involution).
// Makes S^T C-layout regs directly usable as the PV A-fragment.
static __device__ __forceinline__ int sig16(int n) {
  int g2 = (n >> 2) & 3;
  return (g2 == 1 || g2 == 2) ? (n ^ 0xC) : n;
}

typedef __attribute__((address_space(1))) void void_g;
typedef __attribute__((address_space(3))) void void_l;
static __device__ __forceinline__ void gload_lds16(const ushort_t* g, ushort_t* l) {
  __builtin_amdgcn_global_load_lds((void_g*)(ushort_t*)g, (void_l*)l, 16, 0, 0);
}

// ---------------------------------------------------------------------------
// FRAGMENT-MAJOR intermediate layouts:
//  Qb/Kb: [b][kblk = n>>5][c(3)][lane(64)][8]   (lane = (n&31) + 32*((d>>3)&1),
//         elem j = d&7, c = d>>4; d = 0..47, slots 32..47 hold xhat + shift)
//  Vt:    [b][mblk = np>>6][frag(16) = fch*4+kk][lane(64)][8]
//         (lane = (ch&31) + 32*((np>>3)&1), j = np&7; np = sig16-permuted key)
// All attn-side staging DMA sources are lane-contiguous 1KB bursts.
// ---------------------------------------------------------------------------

// ---------------------------------------------------------------------------
// MFMA projections, fused over all 6 bands. R13: wprep FUSED - Wb A-frags +
// biases built in LDS per block (49KB; each thread converts 96 W floats).
// Removes one dispatch + gap; A-frag reads become conflict-free ds_read_b128.
// Coalesced store path via per-wave 32x40 LDS transpose tile (R12).
// Softmax shift folded into slot d=35: Q[35]=-SH2, K[35]=1.0 (uniform per-row
// additive constant -> cancels in O/L normalization) => attn exp2's directly.
// ---------------------------------------------------------------------------
#define TPITCH 40   // ushorts; 80B rows: 16B-aligned b128 reads, 2-way banks (free)
#define WBELEMS (6 * 8 * 64 * 8)   // 24576 ushorts = 48 KB
__global__ __launch_bounds__(256, 2)
void projm2_kernel(const float* __restrict__ x, const float* __restrict__ xyz,
                   const float* __restrict__ Wq, const float* __restrict__ bq,
                   const float* __restrict__ Wk, const float* __restrict__ bk,
                   const float* __restrict__ Wv, const float* __restrict__ bv,
                   ushort_t* __restrict__ Qb, ushort_t* __restrict__ Kb,
                   ushort_t* __restrict__ Vt) {
  __shared__ __align__(16) ushort_t WbL[WBELEMS];
  __shared__ float biasL[192];
  __shared__ __align__(16) ushort_t T[4][32 * TPITCH];
  const int tid = threadIdx.x;
  const int lane = tid & 63, wv = tid >> 6;
  const int l31 = lane & 31, h = lane >> 5;
  const int b = blockIdx.y;
  const int n0 = blockIdx.x * 128 + wv * 32;
  const int n = n0 + l31;

  // B-frags from x (coalesced per c-row), converted once, reused 6x.
  // Issued first so their HBM latency overlaps the Wb build below.
  bf16x8 bfr[8];
  const float* xb = x + (size_t)b * NCH * NPTS + n;
#pragma unroll
  for (int ks = 0; ks < 8; ++ks) {
    const float* xc = xb + (size_t)(ks * 16 + h * 8) * NPTS;
    union { ushort_t u[8]; bf16x8 v; } p;
#pragma unroll
    for (int j = 0; j < 8; ++j) p.u[j] = f2bf(xc[(size_t)j * NPTS]);
    bfr[ks] = p.v;
  }

  // Build Wb fragments in LDS (log2e folded into z=0) + scaled biases.
#pragma unroll
  for (int it = 0; it < 12; ++it) {
    int slot = tid + it * 256;        // 0..3071 = (z*8+ks)*64 + ln
    int zk = slot >> 6, ln = slot & 63;
    int z = zk >> 3, ks = zk & 7;
    const float* W = (z == 0) ? Wq : (z == 1) ? Wk
                                              : (Wv + (size_t)(z - 2) * 32 * 128);
    const float sc = (z == 0) ? LOG2E : 1.0f;
    const float* wr = W + (ln & 31) * 128 + ks * 16 + (ln >> 5) * 8;
    union { ushort_t u[8]; bf16x8 v; } p;
#pragma unroll
    for (int j = 0; j < 8; ++j) p.u[j] = f2bf(wr[j] * sc);
    *(bf16x8*)(WbL + (size_t)slot * 8) = p.v;
  }
  if (tid < 192)
    biasL[tid] = (tid < 32) ? bq[tid] * LOG2E
                            : (tid < 64) ? bk[tid - 32] : bv[tid - 64];
  __syncthreads();

  // xhat (bands 0,1)
  float xa = xyz[((size_t)b * NPTS + n) * 3 + 0];
  float xc2 = xyz[((size_t)b * NPTS + n) * 3 + 1];
  float xd = xyz[((size_t)b * NPTS + n) * 3 + 2];
  float rinv = 1.0f / (sqrtf(xa * xa + xc2 * xc2 + xd * xd) + 1e-8f);

  const int nploc = (l31 & 16) | sig16(l31 & 15);  // V key position within tile
  ushort_t* tw = &T[wv][0];

#pragma unroll 1
  for (int z = 0; z < 6; ++z) {
    f32x16 S;
#pragma unroll
    for (int r = 0; r < 16; ++r)
      S[r] = biasL[z * 32 + (r & 3) + 8 * (r >> 2) + 4 * h];
#pragma unroll
    for (int ks = 0; ks < 8; ++ks) {
      bf16x8 af = *(const bf16x8*)(WbL + ((size_t)(z * 8 + ks) * 64 + lane) * 8);
      S = __builtin_amdgcn_mfma_f32_32x32x16_bf16(af, bfr[ks], S, 0, 0, 0);
    }
    if (z <= 1) {
      // LDS tile [n31][d]: lane holds col n=l31, rows d=(r&3)+8*(r>>2)+4h
#pragma unroll
      for (int r = 0; r < 16; ++r)
        tw[l31 * TPITCH + (r & 3) + 8 * (r >> 2) + 4 * h] = f2bf(S[r]);
      ushort_t* dstf = (z == 0 ? Qb : Kb) +
                       (((size_t)b * 256 + (n0 >> 5)) * 3) * 512;
      // c=0,1 frags: lane = n31 + 32*hb, 8 consecutive d -> 16B read + store
#pragma unroll
      for (int c = 0; c < 2; ++c) {
        bf16x8 fr = *(const bf16x8*)&tw[(lane & 31) * TPITCH + c * 16 + (lane >> 5) * 8];
        *(bf16x8*)(dstf + c * 512 + lane * 8) = fr;
      }
      // c=2 frag: xhat + folded shift, register-direct (already frag-ordered)
      float sc = (z == 0) ? LOG2E : 1.0f;
      float rn = 0.31622776601683794f * sc * rinv;
      union { ushort_t u[16]; bf16x8 v[2]; } t;
#pragma unroll
      for (int j = 0; j < 16; ++j) t.u[j] = 0;
      t.u[0] = f2bf(xa * rn); t.u[1] = f2bf(xc2 * rn); t.u[2] = f2bf(xd * rn);
      t.u[3] = (z == 0) ? f2bf(-SH2) : f2bf(1.0f);  // folded softmax shift (d=35)
      *(bf16x8*)(dstf + 1024 + l31 * 8) = t.v[0];
      *(bf16x8*)(dstf + 1024 + 256 + l31 * 8) = t.v[1];
    } else {
      // LDS tile [ch31][nploc]: transpose n<->ch with sig16 folded in
#pragma unroll
      for (int r = 0; r < 16; ++r)
        tw[((r & 3) + 8 * (r >> 2) + 4 * h) * TPITCH + nploc] = f2bf(S[r]);
      // two complete fragments (16 keys x 32 ch each): coalesced 1KB stores
#pragma unroll
      for (int g = 0; g < 2; ++g) {
        bf16x8 fr = *(const bf16x8*)&tw[(lane & 31) * TPITCH + g * 16 + (lane >> 5) * 8];
        int kk = ((n0 >> 4) + g) & 3;
        ushort_t* dst = Vt + ((((size_t)b * 128 + (n0 >> 6)) * 16 +
                               (z - 2) * 4 + kk) * 512);
        *(bf16x8*)(dst + lane * 8) = fr;
      }
    }
  }
}

// ---------------------------------------------------------------------------
// MFMA flash attention, 32x32x16, 32 q/wave, 8 waves = 256 q/block.
// FROZEN at R12 structure (93us): all-LDS 22-frag staging w/ frag-major
// lane-contiguous 1KB DMA sources, 2-buffer/1-barrier, ~64 arch + 64 acc
// regs -> 4 waves/SIMD. Pipe model per CU-round: LDS 4240 cyc (tallest),
// MFMA 2975, VALU 2600 - overlapped, wall ~ LDS + serialization residue.
// ---------------------------------------------------------------------------
__global__ __launch_bounds__(512, 4)
void attn32_kernel(const ushort_t* __restrict__ Qb, const ushort_t* __restrict__ Kb,
                   const ushort_t* __restrict__ Vt,
                   ushort_t* __restrict__ PACC, float* __restrict__ PL) {
  // frag f: V = fch*4+kk (0..15), K = 16 + kb*3 + c (16..21); 64 lanes x 16B
  __shared__ __align__(16) ushort_t L[2][22][512];
  const int tid = threadIdx.x;
  const int lane = tid & 63, w = tid >> 6;

  const int lin = blockIdx.x;
  const int bs = lin & 15;          // XCD x sees bs in {x, x+8}: 2 (b,seg) combos
  const int b = bs & 3, sseg = bs >> 2;
  const int qblk = lin >> 4;        // 0..31 (256-q blocks)
  const int q0w = qblk * 256 + w * 32;
  const int m00 = sseg * KEYS_PER;

  // persistent Q^T B-frags (frag-major, lane-contiguous)
  bf16x8 qf[3];
  {
    const ushort_t* qbase = Qb + (((size_t)b * 256 + (q0w >> 5)) * 3) * 512 + lane * 8;
#pragma unroll
    for (int c = 0; c < 3; ++c) qf[c] = *(const bf16x8*)(qbase + c * 512);
  }

  // staging sources (frag-major, lane-contiguous): wave w -> frags {w,w+8,w+16}
  const ushort_t* vbase = Vt + (((size_t)b * 128 + (m00 >> 6)) * 16) * 512 + lane * 8;
  const ushort_t* kbase = Kb + (((size_t)b * 256 + (m00 >> 5)) * 3) * 512 + lane * 8;
  const ushort_t* gp[3];
  int fid[3], adv[3];
  const int nf = (w < 6) ? 3 : 2;
#pragma unroll
  for (int i = 0; i < 3; ++i) {
    int fi = w + 8 * i;
    fid[i] = fi;
    if (fi < 16) { gp[i] = vbase + fi * 512; adv[i] = 16 * 512; }
    else if (fi < 22) { gp[i] = kbase + (fi - 16) * 512; adv[i] = 6 * 512; }
  }

  f32x16 O[4];
#pragma unroll
  for (int f = 0; f < 4; ++f) O[f] = (f32x16)(0.f);
  float ls0 = 0.f, ls1 = 0.f;

  // prologue: stage round 0 into buffer 0
#pragma unroll
  for (int i = 0; i < 3; ++i)
    if (i < nf) gload_lds16(gp[i], &L[0][fid[i]][0]);

#pragma unroll 1
  for (int t = 0; t < ROUNDS; ++t) {
    __syncthreads();  // vmcnt(0): buf[t&1] DMA (issued a full round ago) drained
    const int cur = t & 1;
    if (t + 1 < ROUNDS) {
#pragma unroll
      for (int i = 0; i < 3; ++i)
        if (i < nf) {
          gp[i] += adv[i];
          gload_lds16(gp[i], &L[cur ^ 1][fid[i]][0]);  // overlaps compute below
        }
    }

#pragma unroll
    for (int kb = 0; kb < 2; ++kb) {
      bf16x8 kf0 = *(const bf16x8*)(&L[cur][16 + kb * 3 + 0][0] + lane * 8);
      bf16x8 kf1 = *(const bf16x8*)(&L[cur][16 + kb * 3 + 1][0] + lane * 8);
      bf16x8 kf2 = *(const bf16x8*)(&L[cur][16 + kb * 3 + 2][0] + lane * 8);

      __builtin_amdgcn_s_setprio(1);
      f32x16 S = __builtin_amdgcn_mfma_f32_32x32x16_bf16(kf0, qf[0],
                                                         (f32x16)(0.f), 0, 0, 0);
      S = __builtin_amdgcn_mfma_f32_32x32x16_bf16(kf1, qf[1], S, 0, 0, 0);
      S = __builtin_amdgcn_mfma_f32_32x32x16_bf16(kf2, qf[2], S, 0, 0, 0);
      __builtin_amdgcn_s_setprio(0);

      // shift already folded into S via slot 35: p = exp2(S) directly
      uint_t pk[8];
#pragma unroll
      for (int i = 0; i < 8; ++i) {
        float p0 = __builtin_amdgcn_exp2f(S[2 * i]);
        float p1 = __builtin_amdgcn_exp2f(S[2 * i + 1]);
        ls0 += p0;
        ls1 += p1;
        pk[i] = __builtin_amdgcn_perm(__float_as_uint(p1), __float_as_uint(p0),
                                      0x07060302u);
      }

      // sigma16-permuted V => C-regs pack directly into PV A-frags
#pragma unroll
      for (int kkl = 0; kkl < 2; ++kkl) {
        union { uint_t u[4]; bf16x8 v; } au;
        au.u[0] = pk[4 * kkl + 0];
        au.u[1] = pk[4 * kkl + 1];
        au.u[2] = pk[4 * kkl + 2];
        au.u[3] = pk[4 * kkl + 3];
        bf16x8 A = au.v;
        __builtin_amdgcn_s_setprio(1);
#pragma unroll
        for (int f = 0; f < 4; ++f) {
          bf16x8 vf = *(const bf16x8*)(&L[cur][f * 4 + kb * 2 + kkl][0] + lane * 8);
          O[f] = __builtin_amdgcn_mfma_f32_32x32x16_bf16(A, vf, O[f], 0, 0, 0);
        }
        __builtin_amdgcn_s_setprio(0);
      }
    }
  }

  // epilogue: global chunk id = bs*256 + (q>>5)
  float lsum = ls0 + ls1;
  lsum += __shfl_xor(lsum, 32);
  const size_t pbase = (size_t)(bs * 16 + (qblk >> 1)) * 16 + (qblk & 1) * 8 + w;
#pragma unroll
  for (int f = 0; f < 4; ++f) {
    union { ushort_t u[16]; bf16x8 v[2]; } pu;
#pragma unroll
    for (int r = 0; r < 16; ++r) pu.u[r] = f2bf(O[f][r]);
    size_t idx = (pbase * 4 + f) * 1024 + (size_t)lane * 16;
    *(bf16x8*)(PACC + idx) = pu.v[0];
    *(bf16x8*)(PACC + idx + 8) = pu.v[1];
  }
  if (lane < 32) PL[(size_t)bs * NPTS + q0w + lane] = lsum;
}

// ---------------------------------------------------------------------------
// Merge 4 key-split partials + gamma + x, COALESCED output via LDS bounce.
// R13: 2x parallelism - 128-q blocks, grid (64,4,4) = 1024 blocks -> 4
// blocks/CU, 16 waves/CU (was 2 blocks, 2 waves/SIMD). LDS 17.4 KB.
// Phase 1: wave ww owns chunk (q0>>5)+ww: coalesced PACC reads, sum over s,
// x Linv, stage fp32 in LDS. Phase 2: wave -> 8 ch rows, lane -> q=lane*2.
// ---------------------------------------------------------------------------
#define MP2 132
__global__ __launch_bounds__(256, 4)
void merge4c_kernel(const ushort_t* __restrict__ PACC, const float* __restrict__ PL,
                    const float* __restrict__ x, const float* __restrict__ gamma,
                    float* __restrict__ out) {
  __shared__ float Linv[128];
  __shared__ float ldso[32 * MP2];
  const int tid = threadIdx.x;
  const int qb = blockIdx.x, b = blockIdx.y, f = blockIdx.z;
  const int q0 = qb * 128;

  if (tid < 128) {
    float Ls = 0.f;
#pragma unroll
    for (int s = 0; s < 4; ++s)
      Ls += PL[(size_t)(s * 4 + b) * NPTS + q0 + tid];
    Linv[tid] = gamma[0] / Ls;
  }
  __syncthreads();

  const int ww = tid >> 6, lane = tid & 63, l31 = lane & 31, h = lane >> 5;

  // wave ww owns global chunk (s*4+b)*256 + (q0>>5) + ww (32 q x 32 ch)
  float acc[16];
#pragma unroll
  for (int r = 0; r < 16; ++r) acc[r] = 0.f;
#pragma unroll
  for (int s = 0; s < 4; ++s) {
    size_t idx = (((size_t)(s * 4 + b) * 256 + (q0 >> 5) + ww) * 4 + f) * 1024 +
                 (size_t)lane * 16;
    bf16x8 a0 = *(const bf16x8*)(PACC + idx);
    bf16x8 a1 = *(const bf16x8*)(PACC + idx + 8);
#pragma unroll
    for (int r = 0; r < 8; ++r) {
      acc[r] += bf2f((ushort_t)a0[r]);
      acc[8 + r] += bf2f((ushort_t)a1[r]);
    }
  }
  const int qloc = ww * 32 + 4 * h;
#pragma unroll
  for (int rr = 0; rr < 4; ++rr) {
    int q = qloc + 8 * rr;
    f32x4 v;
#pragma unroll
    for (int i = 0; i < 4; ++i) v[i] = acc[rr * 4 + i] * Linv[q + i];
    *(f32x4*)&ldso[l31 * MP2 + q] = v;  // ch_local = l31
  }
  __syncthreads();

  // phase 2: coalesced: wave ww -> ch rows ww*8..+7, lane -> q = lane*2
  const float* xb = x + ((size_t)b * NCH + f * 32) * NPTS + q0;
  float* ob = out + ((size_t)b * NCH + f * 32) * NPTS + q0;
#pragma unroll
  for (int rr = 0; rr < 8; ++rr) {
    int ch = ww * 8 + rr;
    f32x2 v = *(const f32x2*)&ldso[ch * MP2 + lane * 2];
    f32x2 xv = *(const f32x2*)(xb + (size_t)ch * NPTS + lane * 2);
    v += xv;
    *(f32x2*)(ob + (size_t)ch * NPTS + lane * 2) = v;
  }
}

// ---------------------------------------------------------------------------
extern "C" void kernel_launch(void* const* d_in, const int* in_sizes, int n_in,
                              void* d_out, int out_size, void* d_ws,
                              size_t ws_size, hipStream_t stream) {
  const float* x     = (const float*)d_in[0];
  const float* xyz   = (const float*)d_in[1];
  const float* Wq    = (const float*)d_in[2];
  const float* bq    = (const float*)d_in[3];
  const float* Wk    = (const float*)d_in[4];
  const float* bk    = (const float*)d_in[5];
  const float* Wv    = (const float*)d_in[6];
  const float* bv    = (const float*)d_in[7];
  const float* gamma = (const float*)d_in[8];
  float* out = (float*)d_out;

  const size_t BN = (size_t)NB * NPTS;
  ushort_t* Qb = (ushort_t*)d_ws;                 // 4*256*3*512 = BN*DQK
  ushort_t* Kb = Qb + BN * DQK;
  ushort_t* Vt = Kb + BN * DQK;                   // 4*128*16*512 = BN*NCH
  ushort_t* PACC = Vt + BN * NCH;   // 16 bs * 256 chunk * 4 f * 1024
  float* PL = (float*)(PACC + (size_t)16 * 16 * 8 * 2 * 4 * 1024);

  projm2_kernel<<<dim3(NPTS / 128, NB), 256, 0, stream>>>(
      x, xyz, Wq, bq, Wk, bk, Wv, bv, Qb, Kb, Vt);
  attn32_kernel<<<512, 512, 0, stream>>>(Qb, Kb, Vt, PACC, PL);
  merge4c_kernel<<<dim3(64, NB, 4), 256, 0, stream>>>(PACC, PL, x, gamma, out);
  (void)in_sizes; (void)n_in; (void)out_size; (void)ws_size;
}

// Round 7
// 184.476 us; speedup vs baseline: 1.3009x; 1.0023x over previous
//
#include <hip/hip_runtime.h>

#define NPTS 8192
#define NB 4
#define NCH 128
#define DQK 48
#define TK 64
#define SPLIT 4
#define KEYS_PER (NPTS / SPLIT)   // 2048
#define ROUNDS (KEYS_PER / TK)    // 32
#define SH2 28.853901f            // 20 * log2(e)
#define LOG2E 1.4426950408889634f

typedef unsigned short ushort_t;
typedef unsigned int uint_t;
typedef __attribute__((ext_vector_type(8))) short bf16x8;
typedef __attribute__((ext_vector_type(2))) float f32x2;
typedef __attribute__((ext_vector_type(4))) float f32x4;
typedef __attribute__((ext_vector_type(16))) float f32x16;

static __device__ __forceinline__ ushort_t f2bf(float x) {
  union { float f; uint_t u; } v; v.f = x;
  uint_t r = v.u + 0x7fffu + ((v.u >> 16) & 1u);
  return (ushort_t)(r >> 16);
}
static __device__ __forceinline__ float bf2f(ushort_t u) {
  union { uint_t i; float f; } v; v.i = ((uint_t)u) << 16; return v.f;
}
// sigma16: swap middle two 4-blocks of each 16-group (involution).
// Makes S^T C-layout regs directly usable as the PV A-fragment.
static __device__ __forceinline__ int sig16(int n) {
  int g2 = (n >> 2) & 3;
  return (g2 == 1 || g2 == 2) ? (n ^ 0xC) : n;
}

typedef __attribute__((address_space(1))) void void_g;
typedef __attribute__((address_space(3))) void void_l;
static __device__ __forceinline__ void gload_lds16(const ushort_t* g, ushort_t* l) {
  __builtin_amdgcn_global_load_lds((void_g*)(ushort_t*)g, (void_l*)l, 16, 0, 0);
}

// ---------------------------------------------------------------------------
// FRAGMENT-MAJOR intermediate layouts:
//  Qb/Kb: [b][kblk = n>>5][c(3)][lane(64)][8]   (lane = (n&31) + 32*((d>>3)&1),
//         elem j = d&7, c = d>>4; d = 0..47, slots 32..47 hold xhat + shift)
//  Vt:    [b][mblk = np>>6][frag(16) = fch*4+kk][lane(64)][8]
//         (lane = (ch&31) + 32*((np>>3)&1), j = np&7; np = sig16-permuted key)
// All attn-side staging DMA sources are lane-contiguous 1KB bursts.
// ---------------------------------------------------------------------------

// ---------------------------------------------------------------------------
// MFMA projections. R14: 2x TLP. Old grid had 1024 waves (1 wave/SIMD) with
// 64 strided HBM loads/thread -> latency-bound (~8KB in flight vs ~9KB needed
// for BW). Now each 32-pt tile's 6 bands are SPLIT across two waves (half 0:
// z=0,1,2 / half 1: z=3,4,5): 512-thread blocks, 8 waves, 4 tiles -> 2048
// waves = 2 waves/SIMD. Duplicated x B-frag loads L2-hit (HBM unchanged).
// Wb A-frags + biases built in 69KB LDS per block (R13); coalesced store
// path via per-wave 32x40 LDS transpose tile (R12). Softmax shift folded
// into slot d=35: Q[35]=-SH2, K[35]=1.0 => attn exp2's directly.
// ---------------------------------------------------------------------------
#define TPITCH 40   // ushorts; 80B rows: 16B-aligned b128 reads, 2-way banks (free)
#define WBELEMS (6 * 8 * 64 * 8)   // 24576 ushorts = 48 KB
__global__ __launch_bounds__(512, 2)
void projm2_kernel(const float* __restrict__ x, const float* __restrict__ xyz,
                   const float* __restrict__ Wq, const float* __restrict__ bq,
                   const float* __restrict__ Wk, const float* __restrict__ bk,
                   const float* __restrict__ Wv, const float* __restrict__ bv,
                   ushort_t* __restrict__ Qb, ushort_t* __restrict__ Kb,
                   ushort_t* __restrict__ Vt) {
  __shared__ __align__(16) ushort_t WbL[WBELEMS];
  __shared__ float biasL[192];
  __shared__ __align__(16) ushort_t T[8][32 * TPITCH];
  const int tid = threadIdx.x;
  const int lane = tid & 63, wv = tid >> 6;      // wv = 0..7
  const int l31 = lane & 31, h = lane >> 5;
  const int b = blockIdx.y;
  const int tile = wv >> 1, half = wv & 1;       // 4 tiles x 2 band-halves
  const int n0 = blockIdx.x * 128 + tile * 32;
  const int n = n0 + l31;

  // B-frags from x (coalesced per c-row), converted once, reused 3x.
  // Issued first so their HBM latency overlaps the Wb build below.
  bf16x8 bfr[8];
  const float* xb = x + (size_t)b * NCH * NPTS + n;
#pragma unroll
  for (int ks = 0; ks < 8; ++ks) {
    const float* xc = xb + (size_t)(ks * 16 + h * 8) * NPTS;
    union { ushort_t u[8]; bf16x8 v; } p;
#pragma unroll
    for (int j = 0; j < 8; ++j) p.u[j] = f2bf(xc[(size_t)j * NPTS]);
    bfr[ks] = p.v;
  }

  // Build Wb fragments in LDS (log2e folded into z=0) + scaled biases.
#pragma unroll
  for (int it = 0; it < 6; ++it) {
    int slot = tid + it * 512;        // 0..3071 = (z*8+ks)*64 + ln
    int zk = slot >> 6, ln = slot & 63;
    int z = zk >> 3, ks = zk & 7;
    const float* W = (z == 0) ? Wq : (z == 1) ? Wk
                                              : (Wv + (size_t)(z - 2) * 32 * 128);
    const float sc = (z == 0) ? LOG2E : 1.0f;
    const float* wr = W + (ln & 31) * 128 + ks * 16 + (ln >> 5) * 8;
    union { ushort_t u[8]; bf16x8 v; } p;
#pragma unroll
    for (int j = 0; j < 8; ++j) p.u[j] = f2bf(wr[j] * sc);
    *(bf16x8*)(WbL + (size_t)slot * 8) = p.v;
  }
  if (tid < 192)
    biasL[tid] = (tid < 32) ? bq[tid] * LOG2E
                            : (tid < 64) ? bk[tid - 32] : bv[tid - 64];

  // xhat (used by half==0 only; loads are tiny)
  float xa = xyz[((size_t)b * NPTS + n) * 3 + 0];
  float xc2 = xyz[((size_t)b * NPTS + n) * 3 + 1];
  float xd = xyz[((size_t)b * NPTS + n) * 3 + 2];
  float rinv = 1.0f / (sqrtf(xa * xa + xc2 * xc2 + xd * xd) + 1e-8f);

  __syncthreads();

  const int nploc = (l31 & 16) | sig16(l31 & 15);  // V key position within tile
  ushort_t* tw = &T[wv][0];

#pragma unroll 1
  for (int zz = 0; zz < 3; ++zz) {
    const int z = half * 3 + zz;                  // half 0: 0,1,2 / half 1: 3,4,5
    f32x16 S;
#pragma unroll
    for (int r = 0; r < 16; ++r)
      S[r] = biasL[z * 32 + (r & 3) + 8 * (r >> 2) + 4 * h];
#pragma unroll
    for (int ks = 0; ks < 8; ++ks) {
      bf16x8 af = *(const bf16x8*)(WbL + ((size_t)(z * 8 + ks) * 64 + lane) * 8);
      S = __builtin_amdgcn_mfma_f32_32x32x16_bf16(af, bfr[ks], S, 0, 0, 0);
    }
    if (z <= 1) {
      // LDS tile [n31][d]: lane holds col n=l31, rows d=(r&3)+8*(r>>2)+4h
#pragma unroll
      for (int r = 0; r < 16; ++r)
        tw[l31 * TPITCH + (r & 3) + 8 * (r >> 2) + 4 * h] = f2bf(S[r]);
      ushort_t* dstf = (z == 0 ? Qb : Kb) +
                       (((size_t)b * 256 + (n0 >> 5)) * 3) * 512;
      // c=0,1 frags: lane = n31 + 32*hb, 8 consecutive d -> 16B read + store
#pragma unroll
      for (int c = 0; c < 2; ++c) {
        bf16x8 fr = *(const bf16x8*)&tw[(lane & 31) * TPITCH + c * 16 + (lane >> 5) * 8];
        *(bf16x8*)(dstf + c * 512 + lane * 8) = fr;
      }
      // c=2 frag: xhat + folded shift, register-direct (already frag-ordered)
      float sc = (z == 0) ? LOG2E : 1.0f;
      float rn = 0.31622776601683794f * sc * rinv;
      union { ushort_t u[16]; bf16x8 v[2]; } t;
#pragma unroll
      for (int j = 0; j < 16; ++j) t.u[j] = 0;
      t.u[0] = f2bf(xa * rn); t.u[1] = f2bf(xc2 * rn); t.u[2] = f2bf(xd * rn);
      t.u[3] = (z == 0) ? f2bf(-SH2) : f2bf(1.0f);  // folded softmax shift (d=35)
      *(bf16x8*)(dstf + 1024 + l31 * 8) = t.v[0];
      *(bf16x8*)(dstf + 1024 + 256 + l31 * 8) = t.v[1];
    } else {
      // LDS tile [ch31][nploc]: transpose n<->ch with sig16 folded in
#pragma unroll
      for (int r = 0; r < 16; ++r)
        tw[((r & 3) + 8 * (r >> 2) + 4 * h) * TPITCH + nploc] = f2bf(S[r]);
      // two complete fragments (16 keys x 32 ch each): coalesced 1KB stores
#pragma unroll
      for (int g = 0; g < 2; ++g) {
        bf16x8 fr = *(const bf16x8*)&tw[(lane & 31) * TPITCH + g * 16 + (lane >> 5) * 8];
        int kk = ((n0 >> 4) + g) & 3;
        ushort_t* dst = Vt + ((((size_t)b * 128 + (n0 >> 6)) * 16 +
                               (z - 2) * 4 + kk) * 512);
        *(bf16x8*)(dst + lane * 8) = fr;
      }
    }
  }
}

// ---------------------------------------------------------------------------
// MFMA flash attention, 32x32x16, 32 q/wave, 8 waves = 256 q/block.
// FROZEN at R12 structure (93us): all-LDS 22-frag staging w/ frag-major
// lane-contiguous 1KB DMA sources, 2-buffer/1-barrier, ~64 arch + 64 acc
// regs -> 4 waves/SIMD. Pipe model per CU-round: LDS 4240 cyc (tallest),
// MFMA 2975, VALU 2600 - overlapped, wall ~ LDS + serialization residue.
// ---------------------------------------------------------------------------
__global__ __launch_bounds__(512, 4)
void attn32_kernel(const ushort_t* __restrict__ Qb, const ushort_t* __restrict__ Kb,
                   const ushort_t* __restrict__ Vt,
                   ushort_t* __restrict__ PACC, float* __restrict__ PL) {
  // frag f: V = fch*4+kk (0..15), K = 16 + kb*3 + c (16..21); 64 lanes x 16B
  __shared__ __align__(16) ushort_t L[2][22][512];
  const int tid = threadIdx.x;
  const int lane = tid & 63, w = tid >> 6;

  const int lin = blockIdx.x;
  const int bs = lin & 15;          // XCD x sees bs in {x, x+8}: 2 (b,seg) combos
  const int b = bs & 3, sseg = bs >> 2;
  const int qblk = lin >> 4;        // 0..31 (256-q blocks)
  const int q0w = qblk * 256 + w * 32;
  const int m00 = sseg * KEYS_PER;

  // persistent Q^T B-frags (frag-major, lane-contiguous)
  bf16x8 qf[3];
  {
    const ushort_t* qbase = Qb + (((size_t)b * 256 + (q0w >> 5)) * 3) * 512 + lane * 8;
#pragma unroll
    for (int c = 0; c < 3; ++c) qf[c] = *(const bf16x8*)(qbase + c * 512);
  }

  // staging sources (frag-major, lane-contiguous): wave w -> frags {w,w+8,w+16}
  const ushort_t* vbase = Vt + (((size_t)b * 128 + (m00 >> 6)) * 16) * 512 + lane * 8;
  const ushort_t* kbase = Kb + (((size_t)b * 256 + (m00 >> 5)) * 3) * 512 + lane * 8;
  const ushort_t* gp[3];
  int fid[3], adv[3];
  const int nf = (w < 6) ? 3 : 2;
#pragma unroll
  for (int i = 0; i < 3; ++i) {
    int fi = w + 8 * i;
    fid[i] = fi;
    if (fi < 16) { gp[i] = vbase + fi * 512; adv[i] = 16 * 512; }
    else if (fi < 22) { gp[i] = kbase + (fi - 16) * 512; adv[i] = 6 * 512; }
  }

  f32x16 O[4];
#pragma unroll
  for (int f = 0; f < 4; ++f) O[f] = (f32x16)(0.f);
  float ls0 = 0.f, ls1 = 0.f;

  // prologue: stage round 0 into buffer 0
#pragma unroll
  for (int i = 0; i < 3; ++i)
    if (i < nf) gload_lds16(gp[i], &L[0][fid[i]][0]);

#pragma unroll 1
  for (int t = 0; t < ROUNDS; ++t) {
    __syncthreads();  // vmcnt(0): buf[t&1] DMA (issued a full round ago) drained
    const int cur = t & 1;
    if (t + 1 < ROUNDS) {
#pragma unroll
      for (int i = 0; i < 3; ++i)
        if (i < nf) {
          gp[i] += adv[i];
          gload_lds16(gp[i], &L[cur ^ 1][fid[i]][0]);  // overlaps compute below
        }
    }

#pragma unroll
    for (int kb = 0; kb < 2; ++kb) {
      bf16x8 kf0 = *(const bf16x8*)(&L[cur][16 + kb * 3 + 0][0] + lane * 8);
      bf16x8 kf1 = *(const bf16x8*)(&L[cur][16 + kb * 3 + 1][0] + lane * 8);
      bf16x8 kf2 = *(const bf16x8*)(&L[cur][16 + kb * 3 + 2][0] + lane * 8);

      __builtin_amdgcn_s_setprio(1);
      f32x16 S = __builtin_amdgcn_mfma_f32_32x32x16_bf16(kf0, qf[0],
                                                         (f32x16)(0.f), 0, 0, 0);
      S = __builtin_amdgcn_mfma_f32_32x32x16_bf16(kf1, qf[1], S, 0, 0, 0);
      S = __builtin_amdgcn_mfma_f32_32x32x16_bf16(kf2, qf[2], S, 0, 0, 0);
      __builtin_amdgcn_s_setprio(0);

      // shift already folded into S via slot 35: p = exp2(S) directly
      uint_t pk[8];
#pragma unroll
      for (int i = 0; i < 8; ++i) {
        float p0 = __builtin_amdgcn_exp2f(S[2 * i]);
        float p1 = __builtin_amdgcn_exp2f(S[2 * i + 1]);
        ls0 += p0;
        ls1 += p1;
        pk[i] = __builtin_amdgcn_perm(__float_as_uint(p1), __float_as_uint(p0),
                                      0x07060302u);
      }

      // sigma16-permuted V => C-regs pack directly into PV A-frags
#pragma unroll
      for (int kkl = 0; kkl < 2; ++kkl) {
        union { uint_t u[4]; bf16x8 v; } au;
        au.u[0] = pk[4 * kkl + 0];
        au.u[1] = pk[4 * kkl + 1];
        au.u[2] = pk[4 * kkl + 2];
        au.u[3] = pk[4 * kkl + 3];
        bf16x8 A = au.v;
        __builtin_amdgcn_s_setprio(1);
#pragma unroll
        for (int f = 0; f < 4; ++f) {
          bf16x8 vf = *(const bf16x8*)(&L[cur][f * 4 + kb * 2 + kkl][0] + lane * 8);
          O[f] = __builtin_amdgcn_mfma_f32_32x32x16_bf16(A, vf, O[f], 0, 0, 0);
        }
        __builtin_amdgcn_s_setprio(0);
      }
    }
  }

  // epilogue: global chunk id = bs*256 + (q>>5)
  float lsum = ls0 + ls1;
  lsum += __shfl_xor(lsum, 32);
  const size_t pbase = (size_t)(bs * 16 + (qblk >> 1)) * 16 + (qblk & 1) * 8 + w;
#pragma unroll
  for (int f = 0; f < 4; ++f) {
    union { ushort_t u[16]; bf16x8 v[2]; } pu;
#pragma unroll
    for (int r = 0; r < 16; ++r) pu.u[r] = f2bf(O[f][r]);
    size_t idx = (pbase * 4 + f) * 1024 + (size_t)lane * 16;
    *(bf16x8*)(PACC + idx) = pu.v[0];
    *(bf16x8*)(PACC + idx + 8) = pu.v[1];
  }
  if (lane < 32) PL[(size_t)bs * NPTS + q0w + lane] = lsum;
}

// ---------------------------------------------------------------------------
// Merge 4 key-split partials + gamma + x, COALESCED output via LDS bounce.
// 128-q blocks, grid (64,4,4) = 1024 blocks -> 4 blocks/CU, 16 waves/CU.
// Phase 1: wave ww owns chunk (q0>>5)+ww: coalesced PACC reads, sum over s,
// x Linv, stage fp32 in LDS. Phase 2: wave -> 8 ch rows, lane -> q=lane*2.
// ---------------------------------------------------------------------------
#define MP2 132
__global__ __launch_bounds__(256, 4)
void merge4c_kernel(const ushort_t* __restrict__ PACC, const float* __restrict__ PL,
                    const float* __restrict__ x, const float* __restrict__ gamma,
                    float* __restrict__ out) {
  __shared__ float Linv[128];
  __shared__ float ldso[32 * MP2];
  const int tid = threadIdx.x;
  const int qb = blockIdx.x, b = blockIdx.y, f = blockIdx.z;
  const int q0 = qb * 128;

  if (tid < 128) {
    float Ls = 0.f;
#pragma unroll
    for (int s = 0; s < 4; ++s)
      Ls += PL[(size_t)(s * 4 + b) * NPTS + q0 + tid];
    Linv[tid] = gamma[0] / Ls;
  }
  __syncthreads();

  const int ww = tid >> 6, lane = tid & 63, l31 = lane & 31, h = lane >> 5;

  // wave ww owns global chunk (s*4+b)*256 + (q0>>5) + ww (32 q x 32 ch)
  float acc[16];
#pragma unroll
  for (int r = 0; r < 16; ++r) acc[r] = 0.f;
#pragma unroll
  for (int s = 0; s < 4; ++s) {
    size_t idx = (((size_t)(s * 4 + b) * 256 + (q0 >> 5) + ww) * 4 + f) * 1024 +
                 (size_t)lane * 16;
    bf16x8 a0 = *(const bf16x8*)(PACC + idx);
    bf16x8 a1 = *(const bf16x8*)(PACC + idx + 8);
#pragma unroll
    for (int r = 0; r < 8; ++r) {
      acc[r] += bf2f((ushort_t)a0[r]);
      acc[8 + r] += bf2f((ushort_t)a1[r]);
    }
  }
  const int qloc = ww * 32 + 4 * h;
#pragma unroll
  for (int rr = 0; rr < 4; ++rr) {
    int q = qloc + 8 * rr;
    f32x4 v;
#pragma unroll
    for (int i = 0; i < 4; ++i) v[i] = acc[rr * 4 + i] * Linv[q + i];
    *(f32x4*)&ldso[l31 * MP2 + q] = v;  // ch_local = l31
  }
  __syncthreads();

  // phase 2: coalesced: wave ww -> ch rows ww*8..+7, lane -> q = lane*2
  const float* xb = x + ((size_t)b * NCH + f * 32) * NPTS + q0;
  float* ob = out + ((size_t)b * NCH + f * 32) * NPTS + q0;
#pragma unroll
  for (int rr = 0; rr < 8; ++rr) {
    int ch = ww * 8 + rr;
    f32x2 v = *(const f32x2*)&ldso[ch * MP2 + lane * 2];
    f32x2 xv = *(const f32x2*)(xb + (size_t)ch * NPTS + lane * 2);
    v += xv;
    *(f32x2*)(ob + (size_t)ch * NPTS + lane * 2) = v;
  }
}

// ---------------------------------------------------------------------------
extern "C" void kernel_launch(void* const* d_in, const int* in_sizes, int n_in,
                              void* d_out, int out_size, void* d_ws,
                              size_t ws_size, hipStream_t stream) {
  const float* x     = (const float*)d_in[0];
  const float* xyz   = (const float*)d_in[1];
  const float* Wq    = (const float*)d_in[2];
  const float* bq    = (const float*)d_in[3];
  const float* Wk    = (const float*)d_in[4];
  const float* bk    = (const float*)d_in[5];
  const float* Wv    = (const float*)d_in[6];
  const float* bv    = (const float*)d_in[7];
  const float* gamma = (const float*)d_in[8];
  float* out = (float*)d_out;

  const size_t BN = (size_t)NB * NPTS;
  ushort_t* Qb = (ushort_t*)d_ws;                 // 4*256*3*512 = BN*DQK
  ushort_t* Kb = Qb + BN * DQK;
  ushort_t* Vt = Kb + BN * DQK;                   // 4*128*16*512 = BN*NCH
  ushort_t* PACC = Vt + BN * NCH;   // 16 bs * 256 chunk * 4 f * 1024
  float* PL = (float*)(PACC + (size_t)16 * 16 * 8 * 2 * 4 * 1024);

  projm2_kernel<<<dim3(NPTS / 128, NB), 512, 0, stream>>>(
      x, xyz, Wq, bq, Wk, bk, Wv, bv, Qb, Kb, Vt);
  attn32_kernel<<<512, 512, 0, stream>>>(Qb, Kb, Vt, PACC, PL);
  merge4c_kernel<<<dim3(64, NB, 4), 256, 0, stream>>>(PACC, PL, x, gamma, out);
  (void)in_sizes; (void)n_in; (void)out_size; (void)ws_size;
}